// Round 1
// baseline (1416.728 us; speedup 1.0000x reference)
//
#include <hip/hip_runtime.h>
#include <hip/hip_bf16.h>
#include <math.h>

#define N_NODES 50000
#define N_EDGES 400000
#define IN_DIM 256
#define HID 64
#define HEADS 8
#define OUT_DIM 256
#define NEG_SLOPE 0.2f

// ---------------------------------------------------------------------------
// Kernel 1: h[n, hd*64+o] = sum_i x[n,i] * W[hd,i,o]
// Tiled f32 GEMM per head: 64 nodes x 64 outputs per block, 4x4 microtile.
// ---------------------------------------------------------------------------
__global__ __launch_bounds__(256) void gemm_h_kernel(
    const float* __restrict__ x, const float* __restrict__ W,
    float* __restrict__ h)
{
    const int hd = blockIdx.y;
    const int n0 = blockIdx.x * 64;
    const int tid = threadIdx.x;
    const int tx = tid & 15;   // output col group
    const int ty = tid >> 4;   // node row group
    __shared__ float xs[64][17];
    __shared__ float ws[16][65];
    float acc[4][4] = {};
    const float* Wh = W + (size_t)hd * IN_DIM * HID;

    for (int k0 = 0; k0 < IN_DIM; k0 += 16) {
        // stage x tile: 64 rows x 16 k
        {
            int r = tid >> 2;
            int c = (tid & 3) * 4;
            int n = n0 + r; if (n >= N_NODES) n = N_NODES - 1;
            const float4 v = *(const float4*)(x + (size_t)n * IN_DIM + k0 + c);
            xs[r][c] = v.x; xs[r][c+1] = v.y; xs[r][c+2] = v.z; xs[r][c+3] = v.w;
        }
        // stage W tile: 16 k x 64 cols
        {
            int kk = tid >> 4;
            int c = (tid & 15) * 4;
            const float4 v = *(const float4*)(Wh + (size_t)(k0 + kk) * HID + c);
            ws[kk][c] = v.x; ws[kk][c+1] = v.y; ws[kk][c+2] = v.z; ws[kk][c+3] = v.w;
        }
        __syncthreads();
        #pragma unroll
        for (int kk = 0; kk < 16; ++kk) {
            float xv[4], wv[4];
            #pragma unroll
            for (int i = 0; i < 4; ++i) xv[i] = xs[ty*4+i][kk];
            #pragma unroll
            for (int j = 0; j < 4; ++j) wv[j] = ws[kk][tx*4+j];
            #pragma unroll
            for (int i = 0; i < 4; ++i)
                #pragma unroll
                for (int j = 0; j < 4; ++j)
                    acc[i][j] = fmaf(xv[i], wv[j], acc[i][j]);
        }
        __syncthreads();
    }
    #pragma unroll
    for (int i = 0; i < 4; ++i) {
        int n = n0 + ty*4 + i;
        if (n < N_NODES) {
            float4 v = make_float4(acc[i][0], acc[i][1], acc[i][2], acc[i][3]);
            *(float4*)(h + (size_t)n * (HEADS*HID) + hd*HID + tx*4) = v;
        }
    }
}

// ---------------------------------------------------------------------------
// Kernel 2: s_src[n,h] = dot(h[n,h,:], a[h,:64]); s_tgt = dot(h[n,h,:], a[h,64:])
// One wave per (n, head). Lane o holds h[n,h,o].
// ---------------------------------------------------------------------------
__global__ __launch_bounds__(256) void s_kernel(
    const float* __restrict__ h, const float* __restrict__ a,
    float* __restrict__ s_src, float* __restrict__ s_tgt)
{
    const int gid = blockIdx.x * 4 + (threadIdx.x >> 6);  // (n*HEADS + hd)
    const int lane = threadIdx.x & 63;
    if (gid >= N_NODES * HEADS) return;
    const int hd = gid & (HEADS - 1);
    float v = h[(size_t)gid * HID + lane];
    float p = v * a[hd * 2 * HID + lane];
    float q = v * a[hd * 2 * HID + HID + lane];
    #pragma unroll
    for (int off = 32; off > 0; off >>= 1) {
        p += __shfl_down(p, off);
        q += __shfl_down(q, off);
    }
    if (lane == 0) { s_src[gid] = p; s_tgt[gid] = q; }
}

// ---------------------------------------------------------------------------
// Kernel 3: per-edge softmax numerator accumulation into denom[tgt,h].
// No max-subtraction needed: e values are O(1..8), exp() safely in f32 range.
// ---------------------------------------------------------------------------
__global__ __launch_bounds__(256) void edge_pass1(
    const int* __restrict__ ei, const float* __restrict__ s_src,
    const float* __restrict__ s_tgt, float* __restrict__ denom)
{
    const int e = blockIdx.x * 256 + threadIdx.x;
    if (e >= N_EDGES) return;
    const int src = ei[e];
    const int tgt = ei[N_EDGES + e];
    const float4 s0 = *(const float4*)(s_src + (size_t)src * 8);
    const float4 s1 = *(const float4*)(s_src + (size_t)src * 8 + 4);
    const float4 t0 = *(const float4*)(s_tgt + (size_t)tgt * 8);
    const float4 t1 = *(const float4*)(s_tgt + (size_t)tgt * 8 + 4);
    float ev[8] = { s0.x + t0.x, s0.y + t0.y, s0.z + t0.z, s0.w + t0.w,
                    s1.x + t1.x, s1.y + t1.y, s1.z + t1.z, s1.w + t1.w };
    #pragma unroll
    for (int hd = 0; hd < 8; ++hd) {
        float v = ev[hd];
        v = (v >= 0.0f) ? v : NEG_SLOPE * v;
        atomicAdd(&denom[(size_t)tgt * 8 + hd], expf(v));
    }
}

// ---------------------------------------------------------------------------
// Kernel 4 (heavy): per-edge message scatter.
// One wave per edge: lanes 0..7 compute alpha[h], broadcast via shfl,
// then 8 coalesced 256B atomicAdd rows into acc[tgt].
// ---------------------------------------------------------------------------
__global__ __launch_bounds__(256) void edge_pass2(
    const int* __restrict__ ei, const float* __restrict__ s_src,
    const float* __restrict__ s_tgt, const float* __restrict__ denom,
    const float* __restrict__ h, float* __restrict__ acc)
{
    const int wid = blockIdx.x * 4 + (threadIdx.x >> 6);  // edge id
    const int lane = threadIdx.x & 63;
    if (wid >= N_EDGES) return;
    const int src = ei[wid];
    const int tgt = ei[N_EDGES + wid];
    float alpha = 0.0f;
    if (lane < 8) {
        float v = s_src[(size_t)src * 8 + lane] + s_tgt[(size_t)tgt * 8 + lane];
        v = (v >= 0.0f) ? v : NEG_SLOPE * v;
        alpha = expf(v) / (denom[(size_t)tgt * 8 + lane] + 1e-16f);
    }
    const float* hs = h + (size_t)src * (HEADS * HID);
    float* ac = acc + (size_t)tgt * (HEADS * HID);
    #pragma unroll
    for (int hd = 0; hd < 8; ++hd) {
        float a_ = __shfl(alpha, hd);
        atomicAdd(&ac[hd * HID + lane], hs[hd * HID + lane] * a_);
    }
}

// ---------------------------------------------------------------------------
// Kernel 5: out[n,j] = elu( sum_k acc[n,k]*Wo[k,j] + bo[j] )
// Same 64x64 tile structure, K=512.
// ---------------------------------------------------------------------------
__global__ __launch_bounds__(256) void gemm_out_kernel(
    const float* __restrict__ accbuf, const float* __restrict__ Wo,
    const float* __restrict__ bo, float* __restrict__ out)
{
    const int col0 = blockIdx.y * 64;
    const int n0 = blockIdx.x * 64;
    const int tid = threadIdx.x;
    const int tx = tid & 15;
    const int ty = tid >> 4;
    __shared__ float xs[64][17];
    __shared__ float ws[16][65];
    float acc[4][4] = {};
    const int K = HEADS * HID;  // 512

    for (int k0 = 0; k0 < K; k0 += 16) {
        {
            int r = tid >> 2;
            int c = (tid & 3) * 4;
            int n = n0 + r; if (n >= N_NODES) n = N_NODES - 1;
            const float4 v = *(const float4*)(accbuf + (size_t)n * K + k0 + c);
            xs[r][c] = v.x; xs[r][c+1] = v.y; xs[r][c+2] = v.z; xs[r][c+3] = v.w;
        }
        {
            int kk = tid >> 4;
            int c = (tid & 15) * 4;
            const float4 v = *(const float4*)(Wo + (size_t)(k0 + kk) * OUT_DIM + col0 + c);
            ws[kk][c] = v.x; ws[kk][c+1] = v.y; ws[kk][c+2] = v.z; ws[kk][c+3] = v.w;
        }
        __syncthreads();
        #pragma unroll
        for (int kk = 0; kk < 16; ++kk) {
            float xv[4], wv[4];
            #pragma unroll
            for (int i = 0; i < 4; ++i) xv[i] = xs[ty*4+i][kk];
            #pragma unroll
            for (int j = 0; j < 4; ++j) wv[j] = ws[kk][tx*4+j];
            #pragma unroll
            for (int i = 0; i < 4; ++i)
                #pragma unroll
                for (int j = 0; j < 4; ++j)
                    acc[i][j] = fmaf(xv[i], wv[j], acc[i][j]);
        }
        __syncthreads();
    }
    #pragma unroll
    for (int i = 0; i < 4; ++i) {
        int n = n0 + ty*4 + i;
        if (n < N_NODES) {
            float4 v;
            float b0 = bo[col0 + tx*4 + 0], b1 = bo[col0 + tx*4 + 1];
            float b2 = bo[col0 + tx*4 + 2], b3 = bo[col0 + tx*4 + 3];
            float v0 = acc[i][0] + b0, v1 = acc[i][1] + b1;
            float v2 = acc[i][2] + b2, v3 = acc[i][3] + b3;
            v.x = (v0 > 0.0f) ? v0 : expm1f(v0);
            v.y = (v1 > 0.0f) ? v1 : expm1f(v1);
            v.z = (v2 > 0.0f) ? v2 : expm1f(v2);
            v.w = (v3 > 0.0f) ? v3 : expm1f(v3);
            *(float4*)(out + (size_t)n * OUT_DIM + col0 + tx*4) = v;
        }
    }
}

// ---------------------------------------------------------------------------
extern "C" void kernel_launch(void* const* d_in, const int* in_sizes, int n_in,
                              void* d_out, int out_size, void* d_ws, size_t ws_size,
                              hipStream_t stream) {
    const float* x   = (const float*)d_in[0];
    const int*   ei  = (const int*)d_in[1];     // edge_index: [2, E], int32 (jax x64 off)
    const float* W   = (const float*)d_in[2];   // [8, 256, 64]
    const float* a   = (const float*)d_in[3];   // [8, 128]
    const float* Wo  = (const float*)d_in[4];   // [512, 256]
    const float* bo  = (const float*)d_in[5];   // [256]
    float* out = (float*)d_out;

    // workspace layout (floats): h | s_src | s_tgt | denom | acc  (~210 MB)
    float* hbuf  = (float*)d_ws;
    const size_t hsz = (size_t)N_NODES * HEADS * HID;     // 25.6M
    float* s_src = hbuf + hsz;
    float* s_tgt = s_src + (size_t)N_NODES * HEADS;
    float* denom = s_tgt + (size_t)N_NODES * HEADS;
    float* accb  = denom + (size_t)N_NODES * HEADS;

    hipMemsetAsync(denom, 0, (size_t)N_NODES * HEADS * sizeof(float), stream);
    hipMemsetAsync(accb, 0, hsz * sizeof(float), stream);

    dim3 g1((N_NODES + 63) / 64, HEADS);
    gemm_h_kernel<<<g1, 256, 0, stream>>>(x, W, hbuf);

    // N_NODES*HEADS = 400000 waves, 4 waves/block
    s_kernel<<<(N_NODES * HEADS) / 4, 256, 0, stream>>>(hbuf, a, s_src, s_tgt);

    edge_pass1<<<(N_EDGES + 255) / 256, 256, 0, stream>>>(ei, s_src, s_tgt, denom);

    // N_EDGES = 400000 waves, 4 waves/block
    edge_pass2<<<N_EDGES / 4, 256, 0, stream>>>(ei, s_src, s_tgt, denom, hbuf, accb);

    dim3 g5((N_NODES + 63) / 64, OUT_DIM / 64);
    gemm_out_kernel<<<g5, 256, 0, stream>>>(accb, Wo, bo, out);
}

// Round 2
// 834.585 us; speedup vs baseline: 1.6975x; 1.6975x over previous
//
#include <hip/hip_runtime.h>
#include <hip/hip_bf16.h>
#include <math.h>

#define N_NODES 50000
#define N_EDGES 400000
#define IN_DIM 256
#define HID 64
#define HEADS 8
#define OUT_DIM 256
#define NEG_SLOPE 0.2f

// ---------------------------------------------------------------------------
// Kernel 1: h[n, hd*64+o] = sum_i x[n,i] * W[hd,i,o]
// ---------------------------------------------------------------------------
__global__ __launch_bounds__(256) void gemm_h_kernel(
    const float* __restrict__ x, const float* __restrict__ W,
    float* __restrict__ h)
{
    const int hd = blockIdx.y;
    const int n0 = blockIdx.x * 64;
    const int tid = threadIdx.x;
    const int tx = tid & 15;
    const int ty = tid >> 4;
    __shared__ float xs[64][17];
    __shared__ float ws[16][65];
    float acc[4][4] = {};
    const float* Wh = W + (size_t)hd * IN_DIM * HID;

    for (int k0 = 0; k0 < IN_DIM; k0 += 16) {
        {
            int r = tid >> 2;
            int c = (tid & 3) * 4;
            int n = n0 + r; if (n >= N_NODES) n = N_NODES - 1;
            const float4 v = *(const float4*)(x + (size_t)n * IN_DIM + k0 + c);
            xs[r][c] = v.x; xs[r][c+1] = v.y; xs[r][c+2] = v.z; xs[r][c+3] = v.w;
        }
        {
            int kk = tid >> 4;
            int c = (tid & 15) * 4;
            const float4 v = *(const float4*)(Wh + (size_t)(k0 + kk) * HID + c);
            ws[kk][c] = v.x; ws[kk][c+1] = v.y; ws[kk][c+2] = v.z; ws[kk][c+3] = v.w;
        }
        __syncthreads();
        #pragma unroll
        for (int kk = 0; kk < 16; ++kk) {
            float xv[4], wv[4];
            #pragma unroll
            for (int i = 0; i < 4; ++i) xv[i] = xs[ty*4+i][kk];
            #pragma unroll
            for (int j = 0; j < 4; ++j) wv[j] = ws[kk][tx*4+j];
            #pragma unroll
            for (int i = 0; i < 4; ++i)
                #pragma unroll
                for (int j = 0; j < 4; ++j)
                    acc[i][j] = fmaf(xv[i], wv[j], acc[i][j]);
        }
        __syncthreads();
    }
    #pragma unroll
    for (int i = 0; i < 4; ++i) {
        int n = n0 + ty*4 + i;
        if (n < N_NODES) {
            float4 v = make_float4(acc[i][0], acc[i][1], acc[i][2], acc[i][3]);
            *(float4*)(h + (size_t)n * (HEADS*HID) + hd*HID + tx*4) = v;
        }
    }
}

// ---------------------------------------------------------------------------
// Kernel 2: s_src / s_tgt projections
// ---------------------------------------------------------------------------
__global__ __launch_bounds__(256) void s_kernel(
    const float* __restrict__ h, const float* __restrict__ a,
    float* __restrict__ s_src, float* __restrict__ s_tgt)
{
    const int gid = blockIdx.x * 4 + (threadIdx.x >> 6);
    const int lane = threadIdx.x & 63;
    if (gid >= N_NODES * HEADS) return;
    const int hd = gid & (HEADS - 1);
    float v = h[(size_t)gid * HID + lane];
    float p = v * a[hd * 2 * HID + lane];
    float q = v * a[hd * 2 * HID + HID + lane];
    #pragma unroll
    for (int off = 32; off > 0; off >>= 1) {
        p += __shfl_down(p, off);
        q += __shfl_down(q, off);
    }
    if (lane == 0) { s_src[gid] = p; s_tgt[gid] = q; }
}

// ---------------------------------------------------------------------------
// CSR build
// ---------------------------------------------------------------------------
__global__ __launch_bounds__(256) void hist_kernel(
    const int* __restrict__ ei, int* __restrict__ deg)
{
    const int e = blockIdx.x * 256 + threadIdx.x;
    if (e >= N_EDGES) return;
    atomicAdd(&deg[ei[N_EDGES + e]], 1);
}

__global__ __launch_bounds__(1024) void scan_kernel(
    const int* __restrict__ deg, int* __restrict__ base)
{
    __shared__ int partial[1024];
    const int tid = threadIdx.x;
    const int CH = (N_NODES + 1023) / 1024;  // 49
    const int start = tid * CH;
    int sum = 0;
    for (int i = 0; i < CH; ++i) {
        int idx = start + i;
        if (idx < N_NODES) sum += deg[idx];
    }
    partial[tid] = sum;
    __syncthreads();
    for (int off = 1; off < 1024; off <<= 1) {
        int v = (tid >= off) ? partial[tid - off] : 0;
        __syncthreads();
        partial[tid] += v;
        __syncthreads();
    }
    int run = (tid == 0) ? 0 : partial[tid - 1];
    for (int i = 0; i < CH; ++i) {
        int idx = start + i;
        if (idx < N_NODES) {
            base[idx] = run;
            run += deg[idx];
        }
    }
}

__global__ __launch_bounds__(256) void fill_kernel(
    const int* __restrict__ ei, int* __restrict__ base,
    int* __restrict__ csr_src)
{
    const int e = blockIdx.x * 256 + threadIdx.x;
    if (e >= N_EDGES) return;
    const int src = ei[e];
    const int tgt = ei[N_EDGES + e];
    const int pos = atomicAdd(&base[tgt], 1);
    csr_src[pos] = src;
}

// ---------------------------------------------------------------------------
// Fused segment kernel: one wave per target node.
// ---------------------------------------------------------------------------
__global__ __launch_bounds__(256) void segment_kernel(
    const int* __restrict__ endoff, const int* __restrict__ csr_src,
    const float* __restrict__ s_src, const float* __restrict__ s_tgt,
    const float* __restrict__ h, float* __restrict__ acc)
{
    const int t = blockIdx.x * 4 + (threadIdx.x >> 6);
    const int lane = threadIdx.x & 63;
    if (t >= N_NODES) return;
    const int e0 = (t == 0) ? 0 : endoff[t - 1];
    const int e1 = endoff[t];

    float st = 0.0f;
    if (lane < 8) st = s_tgt[(size_t)t * 8 + lane];

    float dsum = 0.0f;
    float msg[8] = {};
    for (int e = e0; e < e1; ++e) {
        const int src = csr_src[e];
        float pv = 0.0f;
        if (lane < 8) {
            float v = s_src[(size_t)src * 8 + lane] + st;
            v = (v >= 0.0f) ? v : NEG_SLOPE * v;
            pv = expf(v);
            dsum += pv;
        }
        const float* hs = h + (size_t)src * (HEADS * HID);
        #pragma unroll
        for (int hd = 0; hd < 8; ++hd) {
            float a_ = __shfl(pv, hd);
            msg[hd] = fmaf(hs[hd * HID + lane], a_, msg[hd]);
        }
    }
    float* ac = acc + (size_t)t * (HEADS * HID);
    #pragma unroll
    for (int hd = 0; hd < 8; ++hd) {
        float d = __shfl(dsum, hd);
        ac[hd * HID + lane] = msg[hd] / (d + 1e-16f);
    }
}

// ---------------------------------------------------------------------------
// Kernel 5: out = elu(acc @ Wo + bo)
// ---------------------------------------------------------------------------
__global__ __launch_bounds__(256) void gemm_out_kernel(
    const float* __restrict__ accbuf, const float* __restrict__ Wo,
    const float* __restrict__ bo, float* __restrict__ out)
{
    const int col0 = blockIdx.y * 64;
    const int n0 = blockIdx.x * 64;
    const int tid = threadIdx.x;
    const int tx = tid & 15;
    const int ty = tid >> 4;
    __shared__ float xs[64][17];
    __shared__ float ws[16][65];
    float acc[4][4] = {};
    const int K = HEADS * HID;  // 512

    for (int k0 = 0; k0 < K; k0 += 16) {
        {
            int r = tid >> 2;
            int c = (tid & 3) * 4;
            int n = n0 + r; if (n >= N_NODES) n = N_NODES - 1;
            const float4 v = *(const float4*)(accbuf + (size_t)n * K + k0 + c);
            xs[r][c] = v.x; xs[r][c+1] = v.y; xs[r][c+2] = v.z; xs[r][c+3] = v.w;
        }
        {
            int kk = tid >> 4;
            int c = (tid & 15) * 4;
            const float4 v = *(const float4*)(Wo + (size_t)(k0 + kk) * OUT_DIM + col0 + c);
            ws[kk][c] = v.x; ws[kk][c+1] = v.y; ws[kk][c+2] = v.z; ws[kk][c+3] = v.w;
        }
        __syncthreads();
        #pragma unroll
        for (int kk = 0; kk < 16; ++kk) {
            float xv[4], wv[4];
            #pragma unroll
            for (int i = 0; i < 4; ++i) xv[i] = xs[ty*4+i][kk];
            #pragma unroll
            for (int j = 0; j < 4; ++j) wv[j] = ws[kk][tx*4+j];
            #pragma unroll
            for (int i = 0; i < 4; ++i)
                #pragma unroll
                for (int j = 0; j < 4; ++j)
                    acc[i][j] = fmaf(xv[i], wv[j], acc[i][j]);
        }
        __syncthreads();
    }
    #pragma unroll
    for (int i = 0; i < 4; ++i) {
        int n = n0 + ty*4 + i;
        if (n < N_NODES) {
            float4 v;
            float b0 = bo[col0 + tx*4 + 0], b1 = bo[col0 + tx*4 + 1];
            float b2 = bo[col0 + tx*4 + 2], b3 = bo[col0 + tx*4 + 3];
            float v0 = acc[i][0] + b0, v1 = acc[i][1] + b1;
            float v2 = acc[i][2] + b2, v3 = acc[i][3] + b3;
            v.x = (v0 > 0.0f) ? v0 : expm1f(v0);
            v.y = (v1 > 0.0f) ? v1 : expm1f(v1);
            v.z = (v2 > 0.0f) ? v2 : expm1f(v2);
            v.w = (v3 > 0.0f) ? v3 : expm1f(v3);
            *(float4*)(out + (size_t)n * OUT_DIM + col0 + tx*4) = v;
        }
    }
}

// ---------------------------------------------------------------------------
extern "C" void kernel_launch(void* const* d_in, const int* in_sizes, int n_in,
                              void* d_out, int out_size, void* d_ws, size_t ws_size,
                              hipStream_t stream) {
    const float* x   = (const float*)d_in[0];
    const int*   ei  = (const int*)d_in[1];
    const float* W   = (const float*)d_in[2];
    const float* a   = (const float*)d_in[3];
    const float* Wo  = (const float*)d_in[4];
    const float* bo  = (const float*)d_in[5];
    float* out = (float*)d_out;

    // workspace: h | s_src | s_tgt | acc | deg | base(end) | csr_src
    float* hbuf  = (float*)d_ws;
    const size_t hsz = (size_t)N_NODES * HEADS * HID;     // 25.6M floats
    float* s_src = hbuf + hsz;
    float* s_tgt = s_src + (size_t)N_NODES * HEADS;
    float* accb  = s_tgt + (size_t)N_NODES * HEADS;
    int*   deg   = (int*)(accb + hsz);
    int*   base  = deg + N_NODES;     // becomes end-offsets after fill
    int*   csr   = base + N_NODES;

    hipMemsetAsync(deg, 0, N_NODES * sizeof(int), stream);

    hist_kernel<<<(N_EDGES + 255) / 256, 256, 0, stream>>>(ei, deg);
    scan_kernel<<<1, 1024, 0, stream>>>(deg, base);
    fill_kernel<<<(N_EDGES + 255) / 256, 256, 0, stream>>>(ei, base, csr);

    dim3 g1((N_NODES + 63) / 64, HEADS);
    gemm_h_kernel<<<g1, 256, 0, stream>>>(x, W, hbuf);
    s_kernel<<<(N_NODES * HEADS) / 4, 256, 0, stream>>>(hbuf, a, s_src, s_tgt);

    segment_kernel<<<(N_NODES + 3) / 4, 256, 0, stream>>>(
        base, csr, s_src, s_tgt, hbuf, accb);

    dim3 g5((N_NODES + 63) / 64, OUT_DIM / 64);
    gemm_out_kernel<<<g5, 256, 0, stream>>>(accb, Wo, bo, out);
}

// Round 3
// 428.972 us; speedup vs baseline: 3.3026x; 1.9455x over previous
//
#include <hip/hip_runtime.h>
#include <hip/hip_bf16.h>
#include <math.h>

#define N_NODES 50000
#define N_EDGES 400000
#define IN_DIM 256
#define HID 64
#define HEADS 8
#define OUT_DIM 256
#define NEG_SLOPE 0.2f

typedef __attribute__((ext_vector_type(8))) short bf16x8;
typedef __attribute__((ext_vector_type(4))) float f32x4;

// RNE float->bf16 (inputs are normal floats; NaN not expected)
static __device__ __forceinline__ unsigned short f2bf(float f) {
    unsigned int u = __float_as_uint(f);
    unsigned int r = (u + 0x7fffu + ((u >> 16) & 1u)) >> 16;
    return (unsigned short)r;
}

// ---------------------------------------------------------------------------
// Converters / transposers
// ---------------------------------------------------------------------------
__global__ __launch_bounds__(256) void cvt_x_kernel(
    const float* __restrict__ x, unsigned short* __restrict__ xb)
{
    const int i = blockIdx.x * 256 + threadIdx.x;           // per float4
    if ((size_t)i * 4 >= (size_t)N_NODES * IN_DIM) return;
    const float4 v = ((const float4*)x)[i];
    ushort4 o;
    o.x = f2bf(v.x); o.y = f2bf(v.y); o.z = f2bf(v.z); o.w = f2bf(v.w);
    ((ushort4*)xb)[i] = o;
}

// W[hd][i][o] -> Wt[hd][o][i]  (B^T layout: k-major per output column)
__global__ __launch_bounds__(256) void cvt_w_kernel(
    const float* __restrict__ W, unsigned short* __restrict__ Wt)
{
    const int i = blockIdx.x * 256 + threadIdx.x;
    if (i >= HEADS * HID * IN_DIM) return;
    const int hd = i >> 14;          // /(64*256)
    const int o  = (i >> 8) & 63;
    const int k  = i & 255;
    Wt[i] = f2bf(W[((size_t)hd * IN_DIM + k) * HID + o]);
}

// Wo[k][n] -> Wot[n][k]
__global__ __launch_bounds__(256) void cvt_wo_kernel(
    const float* __restrict__ Wo, unsigned short* __restrict__ Wot)
{
    const int i = blockIdx.x * 256 + threadIdx.x;
    if (i >= (HEADS * HID) * OUT_DIM) return;
    const int n = i >> 9;            // /512
    const int k = i & 511;
    Wot[i] = f2bf(Wo[(size_t)k * OUT_DIM + n]);
}

// ---------------------------------------------------------------------------
// MFMA GEMM 1: h[m, hd*64+col] = sum_k x[m,k] * W[hd,k,col]   (f32 out)
// Block: 256 thr (4 waves), tile 64(M)x64(N) per head, BK=32.
// LDS is staged in FRAGMENT ORDER: 16B chunk for (row,kgroup) lives at
// unit (row>>4)*64 + kgroup*16 + (row&15); frag read = lds + lane*16B.
// Both staging writes and frag reads are lane-linear -> conflict-free.
// ---------------------------------------------------------------------------
__global__ __launch_bounds__(256) void gemm_h_mfma(
    const unsigned short* __restrict__ xb,   // [N_NODES][256] bf16
    const unsigned short* __restrict__ Wt,   // [8][64][256] bf16
    float* __restrict__ h)                   // [N_NODES][512] f32
{
    const int hd = blockIdx.y;
    const int m0 = blockIdx.x * 64;
    const int tid = threadIdx.x;
    const int w = tid >> 6, lane = tid & 63;
    __shared__ unsigned short lA[64 * 32];
    __shared__ unsigned short lB[64 * 32];

    const int srow = tid >> 2;   // 0..63
    const int skg  = tid & 3;    // 0..3
    const int sunit = (srow >> 4) * 64 + skg * 16 + (srow & 15);
    int arow = m0 + srow; if (arow >= N_NODES) arow = N_NODES - 1;
    const unsigned short* Ap = xb + (size_t)arow * IN_DIM + skg * 8;
    const unsigned short* Bp = Wt + ((size_t)hd * HID + srow) * IN_DIM + skg * 8;

    f32x4 acc[4] = {{0,0,0,0},{0,0,0,0},{0,0,0,0},{0,0,0,0}};
    for (int k0 = 0; k0 < IN_DIM; k0 += 32) {
        *(bf16x8*)(lA + sunit * 8) = *(const bf16x8*)(Ap + k0);
        *(bf16x8*)(lB + sunit * 8) = *(const bf16x8*)(Bp + k0);
        __syncthreads();
        const bf16x8 bfr = *(const bf16x8*)(lB + (w * 64 + lane) * 8);
        #pragma unroll
        for (int t = 0; t < 4; ++t) {
            const bf16x8 afr = *(const bf16x8*)(lA + (t * 64 + lane) * 8);
            acc[t] = __builtin_amdgcn_mfma_f32_16x16x32_bf16(afr, bfr, acc[t], 0, 0, 0);
        }
        __syncthreads();
    }
    // D[m0 + t*16 + (lane>>4)*4 + r][hd*64 + w*16 + (lane&15)]
    const int col = hd * HID + w * 16 + (lane & 15);
    #pragma unroll
    for (int t = 0; t < 4; ++t) {
        #pragma unroll
        for (int r = 0; r < 4; ++r) {
            const int m = m0 + t * 16 + ((lane >> 4) << 2) + r;
            if (m < N_NODES) h[(size_t)m * (HEADS * HID) + col] = acc[t][r];
        }
    }
}

// ---------------------------------------------------------------------------
// MFMA GEMM 2: out = elu(acc @ Wo + bo), A = acc bf16 [50000][512],
// Bt = Wot [256][512], out f32 [50000][256]. Same structure, K=512.
// ---------------------------------------------------------------------------
__global__ __launch_bounds__(256) void gemm_out_mfma(
    const unsigned short* __restrict__ accb,  // [N_NODES][512] bf16
    const unsigned short* __restrict__ Wot,   // [256][512] bf16
    const float* __restrict__ bo,
    float* __restrict__ out)                  // [N_NODES][256] f32
{
    const int n0 = blockIdx.y * 64;
    const int m0 = blockIdx.x * 64;
    const int tid = threadIdx.x;
    const int w = tid >> 6, lane = tid & 63;
    __shared__ unsigned short lA[64 * 32];
    __shared__ unsigned short lB[64 * 32];

    const int srow = tid >> 2;
    const int skg  = tid & 3;
    const int sunit = (srow >> 4) * 64 + skg * 16 + (srow & 15);
    int arow = m0 + srow; if (arow >= N_NODES) arow = N_NODES - 1;
    const unsigned short* Ap = accb + (size_t)arow * (HEADS * HID) + skg * 8;
    const unsigned short* Bp = Wot + (size_t)(n0 + srow) * (HEADS * HID) + skg * 8;

    f32x4 acc[4] = {{0,0,0,0},{0,0,0,0},{0,0,0,0},{0,0,0,0}};
    for (int k0 = 0; k0 < HEADS * HID; k0 += 32) {
        *(bf16x8*)(lA + sunit * 8) = *(const bf16x8*)(Ap + k0);
        *(bf16x8*)(lB + sunit * 8) = *(const bf16x8*)(Bp + k0);
        __syncthreads();
        const bf16x8 bfr = *(const bf16x8*)(lB + (w * 64 + lane) * 8);
        #pragma unroll
        for (int t = 0; t < 4; ++t) {
            const bf16x8 afr = *(const bf16x8*)(lA + (t * 64 + lane) * 8);
            acc[t] = __builtin_amdgcn_mfma_f32_16x16x32_bf16(afr, bfr, acc[t], 0, 0, 0);
        }
        __syncthreads();
    }
    const int col = n0 + w * 16 + (lane & 15);
    const float b = bo[col];
    #pragma unroll
    for (int t = 0; t < 4; ++t) {
        #pragma unroll
        for (int r = 0; r < 4; ++r) {
            const int m = m0 + t * 16 + ((lane >> 4) << 2) + r;
            if (m < N_NODES) {
                float v = acc[t][r] + b;
                out[(size_t)m * OUT_DIM + col] = (v > 0.0f) ? v : expm1f(v);
            }
        }
    }
}

// ---------------------------------------------------------------------------
// s_src / s_tgt projections (reads f32 h)
// ---------------------------------------------------------------------------
__global__ __launch_bounds__(256) void s_kernel(
    const float* __restrict__ h, const float* __restrict__ a,
    float* __restrict__ s_src, float* __restrict__ s_tgt)
{
    const int gid = blockIdx.x * 4 + (threadIdx.x >> 6);
    const int lane = threadIdx.x & 63;
    if (gid >= N_NODES * HEADS) return;
    const int hd = gid & (HEADS - 1);
    float v = h[(size_t)gid * HID + lane];
    float p = v * a[hd * 2 * HID + lane];
    float q = v * a[hd * 2 * HID + HID + lane];
    #pragma unroll
    for (int off = 32; off > 0; off >>= 1) {
        p += __shfl_down(p, off);
        q += __shfl_down(q, off);
    }
    if (lane == 0) { s_src[gid] = p; s_tgt[gid] = q; }
}

// ---------------------------------------------------------------------------
// CSR build
// ---------------------------------------------------------------------------
__global__ __launch_bounds__(256) void hist_kernel(
    const int* __restrict__ ei, int* __restrict__ deg)
{
    const int e = blockIdx.x * 256 + threadIdx.x;
    if (e >= N_EDGES) return;
    atomicAdd(&deg[ei[N_EDGES + e]], 1);
}

__global__ __launch_bounds__(1024) void scan_kernel(
    const int* __restrict__ deg, int* __restrict__ base)
{
    __shared__ int partial[1024];
    const int tid = threadIdx.x;
    const int CH = (N_NODES + 1023) / 1024;  // 49
    const int start = tid * CH;
    int sum = 0;
    for (int i = 0; i < CH; ++i) {
        int idx = start + i;
        if (idx < N_NODES) sum += deg[idx];
    }
    partial[tid] = sum;
    __syncthreads();
    for (int off = 1; off < 1024; off <<= 1) {
        int v = (tid >= off) ? partial[tid - off] : 0;
        __syncthreads();
        partial[tid] += v;
        __syncthreads();
    }
    int run = (tid == 0) ? 0 : partial[tid - 1];
    for (int i = 0; i < CH; ++i) {
        int idx = start + i;
        if (idx < N_NODES) {
            base[idx] = run;
            run += deg[idx];
        }
    }
}

__global__ __launch_bounds__(256) void fill_kernel(
    const int* __restrict__ ei, int* __restrict__ base,
    int* __restrict__ csr_src)
{
    const int e = blockIdx.x * 256 + threadIdx.x;
    if (e >= N_EDGES) return;
    const int src = ei[e];
    const int tgt = ei[N_EDGES + e];
    const int pos = atomicAdd(&base[tgt], 1);
    csr_src[pos] = src;
}

// ---------------------------------------------------------------------------
// Fused segment kernel: one wave per target node; writes acc as bf16.
// ---------------------------------------------------------------------------
__global__ __launch_bounds__(256) void segment_kernel(
    const int* __restrict__ endoff, const int* __restrict__ csr_src,
    const float* __restrict__ s_src, const float* __restrict__ s_tgt,
    const float* __restrict__ h, unsigned short* __restrict__ accb)
{
    const int t = blockIdx.x * 4 + (threadIdx.x >> 6);
    const int lane = threadIdx.x & 63;
    if (t >= N_NODES) return;
    const int e0 = (t == 0) ? 0 : endoff[t - 1];
    const int e1 = endoff[t];

    float st = 0.0f;
    if (lane < 8) st = s_tgt[(size_t)t * 8 + lane];

    float dsum = 0.0f;
    float msg[8] = {};
    for (int e = e0; e < e1; ++e) {
        const int src = csr_src[e];
        float pv = 0.0f;
        if (lane < 8) {
            float v = s_src[(size_t)src * 8 + lane] + st;
            v = (v >= 0.0f) ? v : NEG_SLOPE * v;
            pv = expf(v);
            dsum += pv;
        }
        const float* hs = h + (size_t)src * (HEADS * HID);
        #pragma unroll
        for (int hd = 0; hd < 8; ++hd) {
            float a_ = __shfl(pv, hd);
            msg[hd] = fmaf(hs[hd * HID + lane], a_, msg[hd]);
        }
    }
    unsigned short* ac = accb + (size_t)t * (HEADS * HID);
    #pragma unroll
    for (int hd = 0; hd < 8; ++hd) {
        float d = __shfl(dsum, hd);
        ac[hd * HID + lane] = f2bf(msg[hd] / (d + 1e-16f));
    }
}

// ---------------------------------------------------------------------------
extern "C" void kernel_launch(void* const* d_in, const int* in_sizes, int n_in,
                              void* d_out, int out_size, void* d_ws, size_t ws_size,
                              hipStream_t stream) {
    const float* x   = (const float*)d_in[0];
    const int*   ei  = (const int*)d_in[1];
    const float* W   = (const float*)d_in[2];
    const float* a   = (const float*)d_in[3];
    const float* Wo  = (const float*)d_in[4];
    const float* bo  = (const float*)d_in[5];
    float* out = (float*)d_out;

    // workspace: h(f32) | s_src | s_tgt | xb(bf16) | accb(bf16) | Wt | Wot |
    //            deg | base | csr
    float* hbuf = (float*)d_ws;
    const size_t hsz = (size_t)N_NODES * HEADS * HID;        // 25.6M
    float* s_src = hbuf + hsz;
    float* s_tgt = s_src + (size_t)N_NODES * HEADS;
    unsigned short* xb   = (unsigned short*)(s_tgt + (size_t)N_NODES * HEADS);
    unsigned short* accb = xb + (size_t)N_NODES * IN_DIM;
    unsigned short* Wt   = accb + hsz;
    unsigned short* Wot  = Wt + (size_t)HEADS * HID * IN_DIM;
    int* deg  = (int*)(Wot + (size_t)(HEADS * HID) * OUT_DIM);
    int* base = deg + N_NODES;
    int* csr  = base + N_NODES;

    hipMemsetAsync(deg, 0, N_NODES * sizeof(int), stream);

    // input conversions (independent)
    cvt_x_kernel<<<((N_NODES * IN_DIM / 4) + 255) / 256, 256, 0, stream>>>(x, xb);
    cvt_w_kernel<<<(HEADS * HID * IN_DIM + 255) / 256, 256, 0, stream>>>(W, Wt);
    cvt_wo_kernel<<<((HEADS * HID) * OUT_DIM + 255) / 256, 256, 0, stream>>>(Wo, Wot);

    // CSR build
    hist_kernel<<<(N_EDGES + 255) / 256, 256, 0, stream>>>(ei, deg);
    scan_kernel<<<1, 1024, 0, stream>>>(deg, base);
    fill_kernel<<<(N_EDGES + 255) / 256, 256, 0, stream>>>(ei, base, csr);

    // h = x @ W (per head), MFMA
    dim3 g1((N_NODES + 63) / 64, HEADS);
    gemm_h_mfma<<<g1, 256, 0, stream>>>(xb, Wt, hbuf);

    s_kernel<<<(N_NODES * HEADS) / 4, 256, 0, stream>>>(hbuf, a, s_src, s_tgt);

    segment_kernel<<<(N_NODES + 3) / 4, 256, 0, stream>>>(
        base, csr, s_src, s_tgt, hbuf, accb);

    // out = elu(acc @ Wo + bo), MFMA
    dim3 g5((N_NODES + 63) / 64, OUT_DIM / 64);
    gemm_out_mfma<<<g5, 256, 0, stream>>>(accb, Wot, bo, out);
}

// Round 4
// 332.487 us; speedup vs baseline: 4.2610x; 1.2902x over previous
//
#include <hip/hip_runtime.h>
#include <hip/hip_bf16.h>
#include <math.h>

#define N_NODES 50000
#define N_EDGES 400000
#define IN_DIM 256
#define HID 64
#define HEADS 8
#define OUT_DIM 256
#define NEG_SLOPE 0.2f

typedef __attribute__((ext_vector_type(8))) short bf16x8;
typedef __attribute__((ext_vector_type(4))) float f32x4;

// RNE float->bf16
static __device__ __forceinline__ unsigned short f2bf(float f) {
    unsigned int u = __float_as_uint(f);
    unsigned int r = (u + 0x7fffu + ((u >> 16) & 1u)) >> 16;
    return (unsigned short)r;
}
static __device__ __forceinline__ float bf2f(unsigned short s) {
    return __uint_as_float((unsigned int)s << 16);
}

// ---------------------------------------------------------------------------
// Converters / transposers
// ---------------------------------------------------------------------------
__global__ __launch_bounds__(256) void cvt_x_kernel(
    const float* __restrict__ x, unsigned short* __restrict__ xb)
{
    const int i = blockIdx.x * 256 + threadIdx.x;           // per float4
    if ((size_t)i * 4 >= (size_t)N_NODES * IN_DIM) return;
    const float4 v = ((const float4*)x)[i];
    ushort4 o;
    o.x = f2bf(v.x); o.y = f2bf(v.y); o.z = f2bf(v.z); o.w = f2bf(v.w);
    ((ushort4*)xb)[i] = o;
}

// W[hd][k][o] -> Wt[hd*64+o][k]   (B^T: [512][256])
__global__ __launch_bounds__(256) void cvt_w_kernel(
    const float* __restrict__ W, unsigned short* __restrict__ Wt)
{
    const int i = blockIdx.x * 256 + threadIdx.x;
    if (i >= HEADS * HID * IN_DIM) return;
    const int hd = i >> 14;
    const int o  = (i >> 8) & 63;
    const int k  = i & 255;
    Wt[i] = f2bf(W[((size_t)hd * IN_DIM + k) * HID + o]);
}

// Wo[k][n] -> Wot[n][k]   ([256][512])
__global__ __launch_bounds__(256) void cvt_wo_kernel(
    const float* __restrict__ Wo, unsigned short* __restrict__ Wot)
{
    const int i = blockIdx.x * 256 + threadIdx.x;
    if (i >= (HEADS * HID) * OUT_DIM) return;
    const int n = i >> 9;
    const int k = i & 511;
    Wot[i] = f2bf(Wo[(size_t)k * OUT_DIM + n]);
}

// ---------------------------------------------------------------------------
// Unified MFMA GEMM: C[M][LDC] = A[M][K] @ Bt[N][K]^T  (tile 128x128, BK=64)
// 512 threads = 8 waves (2 M x 4 N), each wave 64x32 output.
// Fragment-order LDS: 16B chunk (row, g) at unit ((row>>4)*8+g)*16+(row&15);
// frag read for row-block R, k-half kk = units R*128+kk*64+lane (lane-linear,
// conflict-free; scheme verified in R3, generalized to BK=64).
// EPI: 0 = store bf16 (h), 1 = +bias, elu, store f32 (out).
// ---------------------------------------------------------------------------
template<int K, int LDC, int EPI>
__global__ __launch_bounds__(512) void gemm_mfma(
    const unsigned short* __restrict__ A,   // [M][K] bf16
    const unsigned short* __restrict__ Bt,  // [N][K] bf16
    const float* __restrict__ bias,
    void* __restrict__ Cv)
{
    const int m0 = blockIdx.x * 128;
    const int n0 = blockIdx.y * 128;
    const int tid = threadIdx.x;
    const int lane = tid & 63;
    const int w = tid >> 6;
    const int wr = w >> 2;          // 0..1 (M)
    const int wn = w & 3;           // 0..3 (N)
    __shared__ unsigned short lA[128 * 64];
    __shared__ unsigned short lB[128 * 64];

    // two staged chunks per thread per buffer: c = tid, tid+512; c = row*8+g
    const int c0 = tid,        r0 = c0 >> 3, g0 = c0 & 7;
    const int c1 = tid + 512,  r1 = c1 >> 3, g1 = c1 & 7;
    const int u0 = (((r0 >> 4) * 8 + g0) * 16) + (r0 & 15);
    const int u1 = (((r1 >> 4) * 8 + g1) * 16) + (r1 & 15);
    int am0 = m0 + r0; if (am0 >= N_NODES) am0 = N_NODES - 1;
    int am1 = m0 + r1; if (am1 >= N_NODES) am1 = N_NODES - 1;
    const unsigned short* Ap0 = A + (size_t)am0 * K + g0 * 8;
    const unsigned short* Ap1 = A + (size_t)am1 * K + g1 * 8;
    const unsigned short* Bp0 = Bt + (size_t)(n0 + r0) * K + g0 * 8;
    const unsigned short* Bp1 = Bt + (size_t)(n0 + r1) * K + g1 * 8;

    f32x4 acc[4][2];
    #pragma unroll
    for (int t = 0; t < 4; ++t)
        #pragma unroll
        for (int n = 0; n < 2; ++n) acc[t][n] = (f32x4){0,0,0,0};

    for (int k0 = 0; k0 < K; k0 += 64) {
        *(bf16x8*)(lA + u0 * 8) = *(const bf16x8*)(Ap0 + k0);
        *(bf16x8*)(lA + u1 * 8) = *(const bf16x8*)(Ap1 + k0);
        *(bf16x8*)(lB + u0 * 8) = *(const bf16x8*)(Bp0 + k0);
        *(bf16x8*)(lB + u1 * 8) = *(const bf16x8*)(Bp1 + k0);
        __syncthreads();
        #pragma unroll
        for (int kk = 0; kk < 2; ++kk) {
            bf16x8 bfr[2];
            #pragma unroll
            for (int n = 0; n < 2; ++n)
                bfr[n] = *(const bf16x8*)(lB + ((wn * 2 + n) * 128 + kk * 64 + lane) * 8);
            #pragma unroll
            for (int t = 0; t < 4; ++t) {
                const bf16x8 afr = *(const bf16x8*)(lA + ((wr * 4 + t) * 128 + kk * 64 + lane) * 8);
                #pragma unroll
                for (int n = 0; n < 2; ++n)
                    acc[t][n] = __builtin_amdgcn_mfma_f32_16x16x32_bf16(afr, bfr[n], acc[t][n], 0, 0, 0);
            }
        }
        __syncthreads();
    }

    #pragma unroll
    for (int n = 0; n < 2; ++n) {
        const int col = n0 + wn * 32 + n * 16 + (lane & 15);
        float b = 0.0f;
        if (EPI == 1) b = bias[col];
        #pragma unroll
        for (int t = 0; t < 4; ++t) {
            #pragma unroll
            for (int r = 0; r < 4; ++r) {
                const int m = m0 + wr * 64 + t * 16 + ((lane >> 4) << 2) + r;
                if (m < N_NODES) {
                    const float v = acc[t][n][r];
                    if (EPI == 0) {
                        ((unsigned short*)Cv)[(size_t)m * LDC + col] = f2bf(v);
                    } else {
                        float z = v + b;
                        ((float*)Cv)[(size_t)m * LDC + col] = (z > 0.0f) ? z : expm1f(z);
                    }
                }
            }
        }
    }
}

// ---------------------------------------------------------------------------
// s projections from bf16 h: one wave per node.
// Lane l owns h[n][l*8 .. l*8+7] (head l>>3); reduce over 8-lane groups.
// ---------------------------------------------------------------------------
__global__ __launch_bounds__(256) void s_kernel(
    const unsigned short* __restrict__ hb, const float* __restrict__ a,
    float* __restrict__ s_src, float* __restrict__ s_tgt)
{
    const int n = blockIdx.x * 4 + (threadIdx.x >> 6);
    const int lane = threadIdx.x & 63;
    if (n >= N_NODES) return;
    const int hd = lane >> 3;
    const int seg = lane & 7;
    const bf16x8 hv = *(const bf16x8*)(hb + (size_t)n * 512 + lane * 8);
    float p = 0.0f, q = 0.0f;
    #pragma unroll
    for (int j = 0; j < 8; ++j) {
        const float hf = bf2f((unsigned short)hv[j]);
        p = fmaf(hf, a[hd * 128 + seg * 8 + j], p);
        q = fmaf(hf, a[hd * 128 + 64 + seg * 8 + j], q);
    }
    #pragma unroll
    for (int off = 1; off < 8; off <<= 1) {
        p += __shfl_xor(p, off);
        q += __shfl_xor(q, off);
    }
    if (seg == 0) {
        s_src[(size_t)n * 8 + hd] = p;
        s_tgt[(size_t)n * 8 + hd] = q;
    }
}

// ---------------------------------------------------------------------------
// CSR build
// ---------------------------------------------------------------------------
__global__ __launch_bounds__(256) void hist_kernel(
    const int* __restrict__ ei, int* __restrict__ deg)
{
    const int e = blockIdx.x * 256 + threadIdx.x;
    if (e >= N_EDGES) return;
    atomicAdd(&deg[ei[N_EDGES + e]], 1);
}

__global__ __launch_bounds__(1024) void scan_kernel(
    const int* __restrict__ deg, int* __restrict__ base)
{
    __shared__ int partial[1024];
    const int tid = threadIdx.x;
    const int CH = (N_NODES + 1023) / 1024;  // 49
    const int start = tid * CH;
    int sum = 0;
    for (int i = 0; i < CH; ++i) {
        int idx = start + i;
        if (idx < N_NODES) sum += deg[idx];
    }
    partial[tid] = sum;
    __syncthreads();
    for (int off = 1; off < 1024; off <<= 1) {
        int v = (tid >= off) ? partial[tid - off] : 0;
        __syncthreads();
        partial[tid] += v;
        __syncthreads();
    }
    int run = (tid == 0) ? 0 : partial[tid - 1];
    for (int i = 0; i < CH; ++i) {
        int idx = start + i;
        if (idx < N_NODES) {
            base[idx] = run;
            run += deg[idx];
        }
    }
}

__global__ __launch_bounds__(256) void fill_kernel(
    const int* __restrict__ ei, int* __restrict__ base,
    int* __restrict__ csr_src)
{
    const int e = blockIdx.x * 256 + threadIdx.x;
    if (e >= N_EDGES) return;
    const int src = ei[e];
    const int tgt = ei[N_EDGES + e];
    const int pos = atomicAdd(&base[tgt], 1);
    csr_src[pos] = src;
}

// ---------------------------------------------------------------------------
// Fused segment kernel: one wave per target node, bf16 h gather.
// Lane l accumulates h[src][l*8..l*8+7] (head l>>3) weighted by alpha.
// ---------------------------------------------------------------------------
__global__ __launch_bounds__(256) void segment_kernel(
    const int* __restrict__ endoff, const int* __restrict__ csr_src,
    const float* __restrict__ s_src, const float* __restrict__ s_tgt,
    const unsigned short* __restrict__ hb, unsigned short* __restrict__ accb)
{
    const int t = blockIdx.x * 4 + (threadIdx.x >> 6);
    const int lane = threadIdx.x & 63;
    if (t >= N_NODES) return;
    const int e0 = (t == 0) ? 0 : endoff[t - 1];
    const int e1 = endoff[t];
    const int myhead = lane >> 3;

    float st = 0.0f;
    if (lane < 8) st = s_tgt[(size_t)t * 8 + lane];

    float dsum = 0.0f;       // per-head denom on lanes 0..7
    float msg[8] = {};
    for (int ebase = e0; ebase < e1; ebase += 64) {
        const int cnt = min(64, e1 - ebase);
        int my_src = 0;
        if (lane < cnt) my_src = csr_src[ebase + lane];
        for (int i = 0; i < cnt; ++i) {
            const int src = __shfl(my_src, i);
            float pv = 0.0f;
            if (lane < 8) {
                float v = s_src[(size_t)src * 8 + lane] + st;
                v = (v >= 0.0f) ? v : NEG_SLOPE * v;
                pv = expf(v);
                dsum += pv;
            }
            const float al = __shfl(pv, myhead);
            const bf16x8 hv = *(const bf16x8*)(hb + (size_t)src * 512 + lane * 8);
            #pragma unroll
            for (int j = 0; j < 8; ++j)
                msg[j] = fmaf(bf2f((unsigned short)hv[j]), al, msg[j]);
        }
    }
    const float d = __shfl(dsum, myhead) + 1e-16f;
    bf16x8 ov;
    #pragma unroll
    for (int j = 0; j < 8; ++j) ov[j] = (short)f2bf(msg[j] / d);
    *(bf16x8*)(accb + (size_t)t * 512 + lane * 8) = ov;
}

// ---------------------------------------------------------------------------
extern "C" void kernel_launch(void* const* d_in, const int* in_sizes, int n_in,
                              void* d_out, int out_size, void* d_ws, size_t ws_size,
                              hipStream_t stream) {
    const float* x   = (const float*)d_in[0];
    const int*   ei  = (const int*)d_in[1];
    const float* W   = (const float*)d_in[2];
    const float* a   = (const float*)d_in[3];
    const float* Wo  = (const float*)d_in[4];
    const float* bo  = (const float*)d_in[5];
    float* out = (float*)d_out;

    // workspace (bf16 h): hb | xb | accb | Wt | Wot | s_src | s_tgt | deg|base|csr
    unsigned short* hb   = (unsigned short*)d_ws;
    const size_t hsz = (size_t)N_NODES * HEADS * HID;        // 25.6M elems
    unsigned short* xb   = hb + hsz;
    unsigned short* accb = xb + (size_t)N_NODES * IN_DIM;
    unsigned short* Wt   = accb + hsz;
    unsigned short* Wot  = Wt + (size_t)HEADS * HID * IN_DIM;
    float* s_src = (float*)(Wot + (size_t)(HEADS * HID) * OUT_DIM);
    float* s_tgt = s_src + (size_t)N_NODES * HEADS;
    int* deg  = (int*)(s_tgt + (size_t)N_NODES * HEADS);
    int* base = deg + N_NODES;
    int* csr  = base + N_NODES;

    hipMemsetAsync(deg, 0, N_NODES * sizeof(int), stream);

    cvt_x_kernel<<<((N_NODES * IN_DIM / 4) + 255) / 256, 256, 0, stream>>>(x, xb);
    cvt_w_kernel<<<(HEADS * HID * IN_DIM + 255) / 256, 256, 0, stream>>>(W, Wt);
    cvt_wo_kernel<<<((HEADS * HID) * OUT_DIM + 255) / 256, 256, 0, stream>>>(Wo, Wot);

    hist_kernel<<<(N_EDGES + 255) / 256, 256, 0, stream>>>(ei, deg);
    scan_kernel<<<1, 1024, 0, stream>>>(deg, base);
    fill_kernel<<<(N_EDGES + 255) / 256, 256, 0, stream>>>(ei, base, csr);

    // h = x @ W  (bf16 out), single GEMM over folded heads
    dim3 g1((N_NODES + 127) / 128, (HEADS * HID) / 128);
    gemm_mfma<IN_DIM, HEADS * HID, 0><<<g1, 512, 0, stream>>>(xb, Wt, nullptr, hb);

    s_kernel<<<(N_NODES + 3) / 4, 256, 0, stream>>>(hb, a, s_src, s_tgt);

    segment_kernel<<<(N_NODES + 3) / 4, 256, 0, stream>>>(
        base, csr, s_src, s_tgt, hb, accb);

    // out = elu(acc @ Wo + bo)
    dim3 g5((N_NODES + 127) / 128, OUT_DIM / 128);
    gemm_mfma<HEADS * HID, OUT_DIM, 1><<<g5, 512, 0, stream>>>(accb, Wot, bo, out);
}

// Round 5
// 247.815 us; speedup vs baseline: 5.7169x; 1.3417x over previous
//
#include <hip/hip_runtime.h>
#include <hip/hip_bf16.h>
#include <math.h>

#define N_NODES 50000
#define N_EDGES 400000
#define IN_DIM 256
#define HID 64
#define HEADS 8
#define OUT_DIM 256
#define NEG_SLOPE 0.2f
#define NSB ((N_NODES + 255) / 256)   // 196 scan blocks

typedef __attribute__((ext_vector_type(8))) short bf16x8;
typedef __attribute__((ext_vector_type(4))) float f32x4;

// RNE float->bf16
static __device__ __forceinline__ unsigned short f2bf(float f) {
    unsigned int u = __float_as_uint(f);
    unsigned int r = (u + 0x7fffu + ((u >> 16) & 1u)) >> 16;
    return (unsigned short)r;
}
static __device__ __forceinline__ float bf2f(unsigned short s) {
    return __uint_as_float((unsigned int)s << 16);
}

// ---------------------------------------------------------------------------
// Converters / transposers
// ---------------------------------------------------------------------------
__global__ __launch_bounds__(256) void cvt_x_kernel(
    const float* __restrict__ x, unsigned short* __restrict__ xb)
{
    const int i = blockIdx.x * 256 + threadIdx.x;           // per float4
    if ((size_t)i * 4 >= (size_t)N_NODES * IN_DIM) return;
    const float4 v = ((const float4*)x)[i];
    ushort4 o;
    o.x = f2bf(v.x); o.y = f2bf(v.y); o.z = f2bf(v.z); o.w = f2bf(v.w);
    ((ushort4*)xb)[i] = o;
}

// W[hd][k][o] -> Wt[hd*64+o][k]   (B^T: [512][256])
__global__ __launch_bounds__(256) void cvt_w_kernel(
    const float* __restrict__ W, unsigned short* __restrict__ Wt)
{
    const int i = blockIdx.x * 256 + threadIdx.x;
    if (i >= HEADS * HID * IN_DIM) return;
    const int hd = i >> 14;
    const int o  = (i >> 8) & 63;
    const int k  = i & 255;
    Wt[i] = f2bf(W[((size_t)hd * IN_DIM + k) * HID + o]);
}

// Wo[k][n] -> Wot[n][k]   ([256][512])
__global__ __launch_bounds__(256) void cvt_wo_kernel(
    const float* __restrict__ Wo, unsigned short* __restrict__ Wot)
{
    const int i = blockIdx.x * 256 + threadIdx.x;
    if (i >= (HEADS * HID) * OUT_DIM) return;
    const int n = i >> 9;
    const int k = i & 511;
    Wot[i] = f2bf(Wo[(size_t)k * OUT_DIM + n]);
}

// ---------------------------------------------------------------------------
// Unified MFMA GEMM: C[M][LDC] = A[M][K] @ Bt[N][K]^T  (tile 128x128, BK=64)
// ---------------------------------------------------------------------------
template<int K, int LDC, int EPI>
__global__ __launch_bounds__(512) void gemm_mfma(
    const unsigned short* __restrict__ A,   // [M][K] bf16
    const unsigned short* __restrict__ Bt,  // [N][K] bf16
    const float* __restrict__ bias,
    void* __restrict__ Cv)
{
    const int m0 = blockIdx.x * 128;
    const int n0 = blockIdx.y * 128;
    const int tid = threadIdx.x;
    const int lane = tid & 63;
    const int w = tid >> 6;
    const int wr = w >> 2;          // 0..1 (M)
    const int wn = w & 3;           // 0..3 (N)
    __shared__ unsigned short lA[128 * 64];
    __shared__ unsigned short lB[128 * 64];

    const int c0 = tid,        r0 = c0 >> 3, g0 = c0 & 7;
    const int c1 = tid + 512,  r1 = c1 >> 3, g1 = c1 & 7;
    const int u0 = (((r0 >> 4) * 8 + g0) * 16) + (r0 & 15);
    const int u1 = (((r1 >> 4) * 8 + g1) * 16) + (r1 & 15);
    int am0 = m0 + r0; if (am0 >= N_NODES) am0 = N_NODES - 1;
    int am1 = m0 + r1; if (am1 >= N_NODES) am1 = N_NODES - 1;
    const unsigned short* Ap0 = A + (size_t)am0 * K + g0 * 8;
    const unsigned short* Ap1 = A + (size_t)am1 * K + g1 * 8;
    const unsigned short* Bp0 = Bt + (size_t)(n0 + r0) * K + g0 * 8;
    const unsigned short* Bp1 = Bt + (size_t)(n0 + r1) * K + g1 * 8;

    f32x4 acc[4][2];
    #pragma unroll
    for (int t = 0; t < 4; ++t)
        #pragma unroll
        for (int n = 0; n < 2; ++n) acc[t][n] = (f32x4){0,0,0,0};

    for (int k0 = 0; k0 < K; k0 += 64) {
        *(bf16x8*)(lA + u0 * 8) = *(const bf16x8*)(Ap0 + k0);
        *(bf16x8*)(lA + u1 * 8) = *(const bf16x8*)(Ap1 + k0);
        *(bf16x8*)(lB + u0 * 8) = *(const bf16x8*)(Bp0 + k0);
        *(bf16x8*)(lB + u1 * 8) = *(const bf16x8*)(Bp1 + k0);
        __syncthreads();
        #pragma unroll
        for (int kk = 0; kk < 2; ++kk) {
            bf16x8 bfr[2];
            #pragma unroll
            for (int n = 0; n < 2; ++n)
                bfr[n] = *(const bf16x8*)(lB + ((wn * 2 + n) * 128 + kk * 64 + lane) * 8);
            #pragma unroll
            for (int t = 0; t < 4; ++t) {
                const bf16x8 afr = *(const bf16x8*)(lA + ((wr * 4 + t) * 128 + kk * 64 + lane) * 8);
                #pragma unroll
                for (int n = 0; n < 2; ++n)
                    acc[t][n] = __builtin_amdgcn_mfma_f32_16x16x32_bf16(afr, bfr[n], acc[t][n], 0, 0, 0);
            }
        }
        __syncthreads();
    }

    #pragma unroll
    for (int n = 0; n < 2; ++n) {
        const int col = n0 + wn * 32 + n * 16 + (lane & 15);
        float b = 0.0f;
        if (EPI == 1) b = bias[col];
        #pragma unroll
        for (int t = 0; t < 4; ++t) {
            #pragma unroll
            for (int r = 0; r < 4; ++r) {
                const int m = m0 + wr * 64 + t * 16 + ((lane >> 4) << 2) + r;
                if (m < N_NODES) {
                    const float v = acc[t][n][r];
                    if (EPI == 0) {
                        ((unsigned short*)Cv)[(size_t)m * LDC + col] = f2bf(v);
                    } else {
                        float z = v + b;
                        ((float*)Cv)[(size_t)m * LDC + col] = (z > 0.0f) ? z : expm1f(z);
                    }
                }
            }
        }
    }
}

// ---------------------------------------------------------------------------
// s projections from bf16 h
// ---------------------------------------------------------------------------
__global__ __launch_bounds__(256) void s_kernel(
    const unsigned short* __restrict__ hb, const float* __restrict__ a,
    float* __restrict__ s_src, float* __restrict__ s_tgt)
{
    const int n = blockIdx.x * 4 + (threadIdx.x >> 6);
    const int lane = threadIdx.x & 63;
    if (n >= N_NODES) return;
    const int hd = lane >> 3;
    const int seg = lane & 7;
    const bf16x8 hv = *(const bf16x8*)(hb + (size_t)n * 512 + lane * 8);
    float p = 0.0f, q = 0.0f;
    #pragma unroll
    for (int j = 0; j < 8; ++j) {
        const float hf = bf2f((unsigned short)hv[j]);
        p = fmaf(hf, a[hd * 128 + seg * 8 + j], p);
        q = fmaf(hf, a[hd * 128 + 64 + seg * 8 + j], q);
    }
    #pragma unroll
    for (int off = 1; off < 8; off <<= 1) {
        p += __shfl_xor(p, off);
        q += __shfl_xor(q, off);
    }
    if (seg == 0) {
        s_src[(size_t)n * 8 + hd] = p;
        s_tgt[(size_t)n * 8 + hd] = q;
    }
}

// ---------------------------------------------------------------------------
// CSR build: hist + hierarchical 3-kernel scan + fill
// ---------------------------------------------------------------------------
__global__ __launch_bounds__(256) void hist_kernel(
    const int* __restrict__ ei, int* __restrict__ deg)
{
    const int e = blockIdx.x * 256 + threadIdx.x;
    if (e >= N_EDGES) return;
    atomicAdd(&deg[ei[N_EDGES + e]], 1);
}

__global__ __launch_bounds__(256) void scan_block_sum(
    const int* __restrict__ deg, int* __restrict__ bsum)
{
    const int i = blockIdx.x * 256 + threadIdx.x;
    int v = (i < N_NODES) ? deg[i] : 0;
    __shared__ int ws_[4];
    #pragma unroll
    for (int off = 32; off > 0; off >>= 1) v += __shfl_down(v, off);
    if ((threadIdx.x & 63) == 0) ws_[threadIdx.x >> 6] = v;
    __syncthreads();
    if (threadIdx.x == 0) bsum[blockIdx.x] = ws_[0] + ws_[1] + ws_[2] + ws_[3];
}

// exclusive scan of NSB (=196) block sums, one 256-thread block
__global__ __launch_bounds__(256) void scan_bsum(
    const int* __restrict__ bsum, int* __restrict__ boff)
{
    __shared__ int s[256];
    const int t = threadIdx.x;
    const int v = (t < NSB) ? bsum[t] : 0;
    s[t] = v;
    __syncthreads();
    for (int off = 1; off < 256; off <<= 1) {
        int u = (t >= off) ? s[t - off] : 0;
        __syncthreads();
        s[t] += u;
        __syncthreads();
    }
    if (t < NSB) boff[t] = s[t] - v;   // exclusive
}

__global__ __launch_bounds__(256) void scan_final(
    const int* __restrict__ deg, const int* __restrict__ boff,
    int* __restrict__ base)
{
    const int i = blockIdx.x * 256 + threadIdx.x;
    const int t = threadIdx.x;
    const int v = (i < N_NODES) ? deg[i] : 0;
    __shared__ int s[256];
    s[t] = v;
    __syncthreads();
    for (int off = 1; off < 256; off <<= 1) {
        int u = (t >= off) ? s[t - off] : 0;
        __syncthreads();
        s[t] += u;
        __syncthreads();
    }
    if (i < N_NODES) base[i] = boff[blockIdx.x] + s[t] - v;
}

__global__ __launch_bounds__(256) void fill_kernel(
    const int* __restrict__ ei, int* __restrict__ base,
    int* __restrict__ csr_src)
{
    const int e = blockIdx.x * 256 + threadIdx.x;
    if (e >= N_EDGES) return;
    const int src = ei[e];
    const int tgt = ei[N_EDGES + e];
    const int pos = atomicAdd(&base[tgt], 1);
    csr_src[pos] = src;
}

// ---------------------------------------------------------------------------
// Fused segment kernel: one wave per target node, bf16 h gather.
// ---------------------------------------------------------------------------
__global__ __launch_bounds__(256) void segment_kernel(
    const int* __restrict__ endoff, const int* __restrict__ csr_src,
    const float* __restrict__ s_src, const float* __restrict__ s_tgt,
    const unsigned short* __restrict__ hb, unsigned short* __restrict__ accb)
{
    const int t = blockIdx.x * 4 + (threadIdx.x >> 6);
    const int lane = threadIdx.x & 63;
    if (t >= N_NODES) return;
    const int e0 = (t == 0) ? 0 : endoff[t - 1];
    const int e1 = endoff[t];
    const int myhead = lane >> 3;

    float st = 0.0f;
    if (lane < 8) st = s_tgt[(size_t)t * 8 + lane];

    float dsum = 0.0f;       // per-head denom on lanes 0..7
    float msg[8] = {};
    for (int ebase = e0; ebase < e1; ebase += 64) {
        const int cnt = min(64, e1 - ebase);
        int my_src = 0;
        if (lane < cnt) my_src = csr_src[ebase + lane];
        for (int i = 0; i < cnt; ++i) {
            const int src = __shfl(my_src, i);
            float pv = 0.0f;
            if (lane < 8) {
                float v = s_src[(size_t)src * 8 + lane] + st;
                v = (v >= 0.0f) ? v : NEG_SLOPE * v;
                pv = expf(v);
                dsum += pv;
            }
            const float al = __shfl(pv, myhead);
            const bf16x8 hv = *(const bf16x8*)(hb + (size_t)src * 512 + lane * 8);
            #pragma unroll
            for (int j = 0; j < 8; ++j)
                msg[j] = fmaf(bf2f((unsigned short)hv[j]), al, msg[j]);
        }
    }
    const float d = __shfl(dsum, myhead) + 1e-16f;
    bf16x8 ov;
    #pragma unroll
    for (int j = 0; j < 8; ++j) ov[j] = (short)f2bf(msg[j] / d);
    *(bf16x8*)(accb + (size_t)t * 512 + lane * 8) = ov;
}

// ---------------------------------------------------------------------------
extern "C" void kernel_launch(void* const* d_in, const int* in_sizes, int n_in,
                              void* d_out, int out_size, void* d_ws, size_t ws_size,
                              hipStream_t stream) {
    const float* x   = (const float*)d_in[0];
    const int*   ei  = (const int*)d_in[1];
    const float* W   = (const float*)d_in[2];
    const float* a   = (const float*)d_in[3];
    const float* Wo  = (const float*)d_in[4];
    const float* bo  = (const float*)d_in[5];
    float* out = (float*)d_out;

    // workspace: hb | xb | accb | Wt | Wot | s_src | s_tgt | deg|base|csr|bsum|boff
    unsigned short* hb   = (unsigned short*)d_ws;
    const size_t hsz = (size_t)N_NODES * HEADS * HID;        // 25.6M elems
    unsigned short* xb   = hb + hsz;
    unsigned short* accb = xb + (size_t)N_NODES * IN_DIM;
    unsigned short* Wt   = accb + hsz;
    unsigned short* Wot  = Wt + (size_t)HEADS * HID * IN_DIM;
    float* s_src = (float*)(Wot + (size_t)(HEADS * HID) * OUT_DIM);
    float* s_tgt = s_src + (size_t)N_NODES * HEADS;
    int* deg  = (int*)(s_tgt + (size_t)N_NODES * HEADS);
    int* base = deg + N_NODES;
    int* csr  = base + N_NODES;
    int* bsum = csr + N_EDGES;
    int* boff = bsum + NSB;

    hipMemsetAsync(deg, 0, N_NODES * sizeof(int), stream);

    cvt_x_kernel<<<((N_NODES * IN_DIM / 4) + 255) / 256, 256, 0, stream>>>(x, xb);
    cvt_w_kernel<<<(HEADS * HID * IN_DIM + 255) / 256, 256, 0, stream>>>(W, Wt);
    cvt_wo_kernel<<<((HEADS * HID) * OUT_DIM + 255) / 256, 256, 0, stream>>>(Wo, Wot);

    hist_kernel<<<(N_EDGES + 255) / 256, 256, 0, stream>>>(ei, deg);
    scan_block_sum<<<NSB, 256, 0, stream>>>(deg, bsum);
    scan_bsum<<<1, 256, 0, stream>>>(bsum, boff);
    scan_final<<<NSB, 256, 0, stream>>>(deg, boff, base);
    fill_kernel<<<(N_EDGES + 255) / 256, 256, 0, stream>>>(ei, base, csr);

    // h = x @ W  (bf16 out), single GEMM over folded heads
    dim3 g1((N_NODES + 127) / 128, (HEADS * HID) / 128);
    gemm_mfma<IN_DIM, HEADS * HID, 0><<<g1, 512, 0, stream>>>(xb, Wt, nullptr, hb);

    s_kernel<<<(N_NODES + 3) / 4, 256, 0, stream>>>(hb, a, s_src, s_tgt);

    segment_kernel<<<(N_NODES + 3) / 4, 256, 0, stream>>>(
        base, csr, s_src, s_tgt, hb, accb);

    // out = elu(acc @ Wo + bo)
    dim3 g5((N_NODES + 127) / 128, OUT_DIM / 128);
    gemm_mfma<HEADS * HID, OUT_DIM, 1><<<g5, 512, 0, stream>>>(accb, Wot, bo, out);
}

// Round 7
// 233.550 us; speedup vs baseline: 6.0661x; 1.0611x over previous
//
#include <hip/hip_runtime.h>
#include <hip/hip_bf16.h>
#include <math.h>

#define N_NODES 50000
#define N_EDGES 400000
#define IN_DIM 256
#define HID 64
#define HEADS 8
#define OUT_DIM 256
#define NEG_SLOPE 0.2f
#define NSB ((N_NODES + 255) / 256)   // 196 scan blocks

// prep_kernel block ranges
#define CVTX_BLOCKS 12500             // 50000*256/4/256 exact
#define CVTW_BLOCKS 512               // 131072/256 exact
#define CVTWO_BLOCKS 512
#define HIST_BLOCKS 1563

typedef __attribute__((ext_vector_type(8))) short bf16x8;
typedef __attribute__((ext_vector_type(4))) float f32x4;

// RNE float->bf16
static __device__ __forceinline__ unsigned short f2bf(float f) {
    unsigned int u = __float_as_uint(f);
    unsigned int r = (u + 0x7fffu + ((u >> 16) & 1u)) >> 16;
    return (unsigned short)r;
}
static __device__ __forceinline__ float bf2f(unsigned short s) {
    return __uint_as_float((unsigned int)s << 16);
}

// ---------------------------------------------------------------------------
// Fused prologue: cvt_x | cvt_w | cvt_wo | hist by blockIdx range.
// ---------------------------------------------------------------------------
__global__ __launch_bounds__(256) void prep_kernel(
    const float* __restrict__ x, unsigned short* __restrict__ xb,
    const float* __restrict__ W, unsigned short* __restrict__ Wt,
    const float* __restrict__ Wo, unsigned short* __restrict__ Wot,
    const int* __restrict__ ei, int* __restrict__ deg)
{
    const int b = blockIdx.x;
    if (b < CVTX_BLOCKS) {
        const int i = b * 256 + threadIdx.x;          // per float4, exact
        const float4 v = ((const float4*)x)[i];
        ushort4 o;
        o.x = f2bf(v.x); o.y = f2bf(v.y); o.z = f2bf(v.z); o.w = f2bf(v.w);
        ((ushort4*)xb)[i] = o;
    } else if (b < CVTX_BLOCKS + CVTW_BLOCKS) {
        // W[hd][k][o] -> Wt[hd*64+o][k]
        const int i = (b - CVTX_BLOCKS) * 256 + threadIdx.x;
        const int hd = i >> 14;
        const int o  = (i >> 8) & 63;
        const int k  = i & 255;
        Wt[i] = f2bf(W[((size_t)hd * IN_DIM + k) * HID + o]);
    } else if (b < CVTX_BLOCKS + CVTW_BLOCKS + CVTWO_BLOCKS) {
        // Wo[k][n] -> Wot[n][k]
        const int i = (b - CVTX_BLOCKS - CVTW_BLOCKS) * 256 + threadIdx.x;
        const int n = i >> 9;
        const int k = i & 511;
        Wot[i] = f2bf(Wo[(size_t)k * OUT_DIM + n]);
    } else {
        const int e = (b - CVTX_BLOCKS - CVTW_BLOCKS - CVTWO_BLOCKS) * 256 + threadIdx.x;
        if (e < N_EDGES) atomicAdd(&deg[ei[N_EDGES + e]], 1);
    }
}

// ---------------------------------------------------------------------------
// Unified MFMA GEMM: C[M][LDC] = A[M][K] @ Bt[N][K]^T  (tile 128x128, BK=64)
// ---------------------------------------------------------------------------
template<int K, int LDC, int EPI>
__global__ __launch_bounds__(512) void gemm_mfma(
    const unsigned short* __restrict__ A,   // [M][K] bf16
    const unsigned short* __restrict__ Bt,  // [N][K] bf16
    const float* __restrict__ bias,
    void* __restrict__ Cv)
{
    const int m0 = blockIdx.x * 128;
    const int n0 = blockIdx.y * 128;
    const int tid = threadIdx.x;
    const int lane = tid & 63;
    const int w = tid >> 6;
    const int wr = w >> 2;          // 0..1 (M)
    const int wn = w & 3;           // 0..3 (N)
    __shared__ unsigned short lA[128 * 64];
    __shared__ unsigned short lB[128 * 64];

    const int c0 = tid,        r0 = c0 >> 3, g0 = c0 & 7;
    const int c1 = tid + 512,  r1 = c1 >> 3, g1 = c1 & 7;
    const int u0 = (((r0 >> 4) * 8 + g0) * 16) + (r0 & 15);
    const int u1 = (((r1 >> 4) * 8 + g1) * 16) + (r1 & 15);
    int am0 = m0 + r0; if (am0 >= N_NODES) am0 = N_NODES - 1;
    int am1 = m0 + r1; if (am1 >= N_NODES) am1 = N_NODES - 1;
    const unsigned short* Ap0 = A + (size_t)am0 * K + g0 * 8;
    const unsigned short* Ap1 = A + (size_t)am1 * K + g1 * 8;
    const unsigned short* Bp0 = Bt + (size_t)(n0 + r0) * K + g0 * 8;
    const unsigned short* Bp1 = Bt + (size_t)(n0 + r1) * K + g1 * 8;

    f32x4 acc[4][2];
    #pragma unroll
    for (int t = 0; t < 4; ++t)
        #pragma unroll
        for (int n = 0; n < 2; ++n) acc[t][n] = (f32x4){0,0,0,0};

    for (int k0 = 0; k0 < K; k0 += 64) {
        *(bf16x8*)(lA + u0 * 8) = *(const bf16x8*)(Ap0 + k0);
        *(bf16x8*)(lA + u1 * 8) = *(const bf16x8*)(Ap1 + k0);
        *(bf16x8*)(lB + u0 * 8) = *(const bf16x8*)(Bp0 + k0);
        *(bf16x8*)(lB + u1 * 8) = *(const bf16x8*)(Bp1 + k0);
        __syncthreads();
        #pragma unroll
        for (int kk = 0; kk < 2; ++kk) {
            bf16x8 bfr[2];
            #pragma unroll
            for (int n = 0; n < 2; ++n)
                bfr[n] = *(const bf16x8*)(lB + ((wn * 2 + n) * 128 + kk * 64 + lane) * 8);
            #pragma unroll
            for (int t = 0; t < 4; ++t) {
                const bf16x8 afr = *(const bf16x8*)(lA + ((wr * 4 + t) * 128 + kk * 64 + lane) * 8);
                #pragma unroll
                for (int n = 0; n < 2; ++n)
                    acc[t][n] = __builtin_amdgcn_mfma_f32_16x16x32_bf16(afr, bfr[n], acc[t][n], 0, 0, 0);
            }
        }
        __syncthreads();
    }

    #pragma unroll
    for (int n = 0; n < 2; ++n) {
        const int col = n0 + wn * 32 + n * 16 + (lane & 15);
        float b = 0.0f;
        if (EPI == 1) b = bias[col];
        #pragma unroll
        for (int t = 0; t < 4; ++t) {
            #pragma unroll
            for (int r = 0; r < 4; ++r) {
                const int m = m0 + wr * 64 + t * 16 + ((lane >> 4) << 2) + r;
                if (m < N_NODES) {
                    const float v = acc[t][n][r];
                    if (EPI == 0) {
                        ((unsigned short*)Cv)[(size_t)m * LDC + col] = f2bf(v);
                    } else {
                        float z = v + b;
                        ((float*)Cv)[(size_t)m * LDC + col] = (z > 0.0f) ? z : expm1f(z);
                    }
                }
            }
        }
    }
}

// ---------------------------------------------------------------------------
// s projections from bf16 h
// ---------------------------------------------------------------------------
__global__ __launch_bounds__(256) void s_kernel(
    const unsigned short* __restrict__ hb, const float* __restrict__ a,
    float* __restrict__ s_src, float* __restrict__ s_tgt)
{
    const int n = blockIdx.x * 4 + (threadIdx.x >> 6);
    const int lane = threadIdx.x & 63;
    if (n >= N_NODES) return;
    const int hd = lane >> 3;
    const int seg = lane & 7;
    const bf16x8 hv = *(const bf16x8*)(hb + (size_t)n * 512 + lane * 8);
    float p = 0.0f, q = 0.0f;
    #pragma unroll
    for (int j = 0; j < 8; ++j) {
        const float hf = bf2f((unsigned short)hv[j]);
        p = fmaf(hf, a[hd * 128 + seg * 8 + j], p);
        q = fmaf(hf, a[hd * 128 + 64 + seg * 8 + j], q);
    }
    #pragma unroll
    for (int off = 1; off < 8; off <<= 1) {
        p += __shfl_xor(p, off);
        q += __shfl_xor(q, off);
    }
    if (seg == 0) {
        s_src[(size_t)n * 8 + hd] = p;
        s_tgt[(size_t)n * 8 + hd] = q;
    }
}

// ---------------------------------------------------------------------------
// Hierarchical scan (3 kernels) + fill
// ---------------------------------------------------------------------------
__global__ __launch_bounds__(256) void scan_block_sum(
    const int* __restrict__ deg, int* __restrict__ bsum)
{
    const int i = blockIdx.x * 256 + threadIdx.x;
    int v = (i < N_NODES) ? deg[i] : 0;
    __shared__ int ws_[4];
    #pragma unroll
    for (int off = 32; off > 0; off >>= 1) v += __shfl_down(v, off);
    if ((threadIdx.x & 63) == 0) ws_[threadIdx.x >> 6] = v;
    __syncthreads();
    if (threadIdx.x == 0) bsum[blockIdx.x] = ws_[0] + ws_[1] + ws_[2] + ws_[3];
}

__global__ __launch_bounds__(256) void scan_bsum(
    const int* __restrict__ bsum, int* __restrict__ boff)
{
    __shared__ int s[256];
    const int t = threadIdx.x;
    const int v = (t < NSB) ? bsum[t] : 0;
    s[t] = v;
    __syncthreads();
    for (int off = 1; off < 256; off <<= 1) {
        int u = (t >= off) ? s[t - off] : 0;
        __syncthreads();
        s[t] += u;
        __syncthreads();
    }
    if (t < NSB) boff[t] = s[t] - v;   // exclusive
}

__global__ __launch_bounds__(256) void scan_final(
    const int* __restrict__ deg, const int* __restrict__ boff,
    int* __restrict__ base)
{
    const int i = blockIdx.x * 256 + threadIdx.x;
    const int t = threadIdx.x;
    const int v = (i < N_NODES) ? deg[i] : 0;
    __shared__ int s[256];
    s[t] = v;
    __syncthreads();
    for (int off = 1; off < 256; off <<= 1) {
        int u = (t >= off) ? s[t - off] : 0;
        __syncthreads();
        s[t] += u;
        __syncthreads();
    }
    if (i < N_NODES) base[i] = boff[blockIdx.x] + s[t] - v;
}

__global__ __launch_bounds__(256) void fill_kernel(
    const int* __restrict__ ei, int* __restrict__ base,
    int* __restrict__ csr_src)
{
    const int e = blockIdx.x * 256 + threadIdx.x;
    if (e >= N_EDGES) return;
    const int src = ei[e];
    const int tgt = ei[N_EDGES + e];
    const int pos = atomicAdd(&base[tgt], 1);
    csr_src[pos] = src;
}

// ---------------------------------------------------------------------------
// Fused segment kernel v2 (fixed): one wave per target node.
// alpha batched 8-edges-wide; ALL __shfl hoisted to wave-uniform control
// flow (ds_bpermute publishes only ACTIVE lanes -> a shfl inside a
// divergent branch reads garbage when its source lane is masked off;
// this was R6's correctness bug for segments with cnt%8 in {1..b}).
// ---------------------------------------------------------------------------
__global__ __launch_bounds__(256) void segment_kernel(
    const int* __restrict__ endoff, const int* __restrict__ csr_src,
    const float* __restrict__ s_src, const float* __restrict__ s_tgt,
    const unsigned short* __restrict__ hb, unsigned short* __restrict__ accb)
{
    const int t = blockIdx.x * 4 + (threadIdx.x >> 6);
    const int lane = threadIdx.x & 63;
    if (t >= N_NODES) return;
    const int e0 = (t == 0) ? 0 : endoff[t - 1];
    const int e1 = endoff[t];
    const int myhead = lane >> 3;    // head owned in gather/output
    const int islot = lane >> 3;     // edge slot in pv batch (same bits)
    const int pj = lane & 7;         // head in pv batch

    const float st = s_tgt[(size_t)t * 8 + pj];

    float dsum = 0.0f;               // partial denom: (slot islot, head pj)
    float msg[8] = {};
    for (int ebase = e0; ebase < e1; ebase += 64) {
        const int cnt = min(64, e1 - ebase);
        int my_src = 0;
        if (lane < cnt) my_src = csr_src[ebase + lane];
        for (int b = 0; b * 8 < cnt; ++b) {
            const int nb = min(8, cnt - b * 8);
            // ---- batched alpha numerators: 8 edges x 8 heads on 64 lanes.
            // shfl OUTSIDE the divergent if (uniform exec -> all lanes publish).
            const int esrc = __shfl(my_src, b * 8 + islot);
            float pv = 0.0f;
            if (islot < nb) {
                float v = s_src[(size_t)esrc * 8 + pj] + st;
                v = (v >= 0.0f) ? v : NEG_SLOPE * v;
                pv = expf(v);
            }
            dsum += pv;
            // ---- gather + weighted accumulate, unroll x4 for MLP
            int i = 0;
            for (; i + 4 <= nb; i += 4) {
                int  sr[4]; float al[4]; bf16x8 hv[4];
                #pragma unroll
                for (int u = 0; u < 4; ++u) {
                    sr[u] = __shfl(my_src, b * 8 + i + u);
                    al[u] = __shfl(pv, (i + u) * 8 + myhead);
                }
                #pragma unroll
                for (int u = 0; u < 4; ++u)
                    hv[u] = *(const bf16x8*)(hb + (size_t)sr[u] * 512 + lane * 8);
                #pragma unroll
                for (int u = 0; u < 4; ++u)
                    #pragma unroll
                    for (int j = 0; j < 8; ++j)
                        msg[j] = fmaf(bf2f((unsigned short)hv[u][j]), al[u], msg[j]);
            }
            for (; i < nb; ++i) {
                const int src = __shfl(my_src, b * 8 + i);
                const float al = __shfl(pv, i * 8 + myhead);
                const bf16x8 hv = *(const bf16x8*)(hb + (size_t)src * 512 + lane * 8);
                #pragma unroll
                for (int j = 0; j < 8; ++j)
                    msg[j] = fmaf(bf2f((unsigned short)hv[j]), al, msg[j]);
            }
        }
    }
    // cross-slot denom reduce: lane l -> full denom for head l&7
    dsum += __shfl_xor(dsum, 8);
    dsum += __shfl_xor(dsum, 16);
    dsum += __shfl_xor(dsum, 32);
    const float d = __shfl(dsum, myhead) + 1e-16f;   // denom for head l>>3
    bf16x8 ov;
    #pragma unroll
    for (int j = 0; j < 8; ++j) ov[j] = (short)f2bf(msg[j] / d);
    *(bf16x8*)(accb + (size_t)t * 512 + lane * 8) = ov;
}

// ---------------------------------------------------------------------------
extern "C" void kernel_launch(void* const* d_in, const int* in_sizes, int n_in,
                              void* d_out, int out_size, void* d_ws, size_t ws_size,
                              hipStream_t stream) {
    const float* x   = (const float*)d_in[0];
    const int*   ei  = (const int*)d_in[1];
    const float* W   = (const float*)d_in[2];
    const float* a   = (const float*)d_in[3];
    const float* Wo  = (const float*)d_in[4];
    const float* bo  = (const float*)d_in[5];
    float* out = (float*)d_out;

    // workspace: hb | xb | accb | Wt | Wot | s_src | s_tgt | deg|base|csr|bsum|boff
    unsigned short* hb   = (unsigned short*)d_ws;
    const size_t hsz = (size_t)N_NODES * HEADS * HID;        // 25.6M elems
    unsigned short* xb   = hb + hsz;
    unsigned short* accb = xb + (size_t)N_NODES * IN_DIM;
    unsigned short* Wt   = accb + hsz;
    unsigned short* Wot  = Wt + (size_t)HEADS * HID * IN_DIM;
    float* s_src = (float*)(Wot + (size_t)(HEADS * HID) * OUT_DIM);
    float* s_tgt = s_src + (size_t)N_NODES * HEADS;
    int* deg  = (int*)(s_tgt + (size_t)N_NODES * HEADS);
    int* base = deg + N_NODES;
    int* csr  = base + N_NODES;
    int* bsum = csr + N_EDGES;
    int* boff = bsum + NSB;

    hipMemsetAsync(deg, 0, N_NODES * sizeof(int), stream);

    prep_kernel<<<CVTX_BLOCKS + CVTW_BLOCKS + CVTWO_BLOCKS + HIST_BLOCKS,
                  256, 0, stream>>>(x, xb, W, Wt, Wo, Wot, ei, deg);

    scan_block_sum<<<NSB, 256, 0, stream>>>(deg, bsum);
    scan_bsum<<<1, 256, 0, stream>>>(bsum, boff);
    scan_final<<<NSB, 256, 0, stream>>>(deg, boff, base);
    fill_kernel<<<(N_EDGES + 255) / 256, 256, 0, stream>>>(ei, base, csr);

    // h = x @ W  (bf16 out), single GEMM over folded heads
    dim3 g1((N_NODES + 127) / 128, (HEADS * HID) / 128);
    gemm_mfma<IN_DIM, HEADS * HID, 0><<<g1, 512, 0, stream>>>(xb, Wt, nullptr, hb);

    s_kernel<<<(N_NODES + 3) / 4, 256, 0, stream>>>(hb, a, s_src, s_tgt);

    segment_kernel<<<(N_NODES + 3) / 4, 256, 0, stream>>>(
        base, csr, s_src, s_tgt, hb, accb);

    // out = elu(acc @ Wo + bo)
    dim3 g5((N_NODES + 127) / 128, OUT_DIM / 128);
    gemm_mfma<HEADS * HID, OUT_DIM, 1><<<g5, 512, 0, stream>>>(accb, Wot, bo, out);
}

// Round 9
// 232.339 us; speedup vs baseline: 6.0977x; 1.0052x over previous
//
#include <hip/hip_runtime.h>
#include <hip/hip_bf16.h>
#include <math.h>

#define N_NODES 50000
#define N_EDGES 400000
#define IN_DIM 256
#define HID 64
#define HEADS 8
#define OUT_DIM 256
#define NEG_SLOPE 0.2f
#define NSB ((N_NODES + 255) / 256)   // 196 scan blocks

// prep_kernel block ranges
#define CVTX_BLOCKS 12500             // 50000*256/4/256 exact
#define CVTW_BLOCKS 512               // 131072/256 exact
#define CVTWO_BLOCKS 512
#define HIST_BLOCKS 1563

typedef __attribute__((ext_vector_type(8))) short bf16x8;
typedef __attribute__((ext_vector_type(4))) float f32x4;

// RNE float->bf16
static __device__ __forceinline__ unsigned short f2bf(float f) {
    unsigned int u = __float_as_uint(f);
    unsigned int r = (u + 0x7fffu + ((u >> 16) & 1u)) >> 16;
    return (unsigned short)r;
}
static __device__ __forceinline__ float bf2f(unsigned short s) {
    return __uint_as_float((unsigned int)s << 16);
}

// ---------------------------------------------------------------------------
// Fused prologue: cvt_x | cvt_w | cvt_wo | hist by blockIdx range.
// ---------------------------------------------------------------------------
__global__ __launch_bounds__(256) void prep_kernel(
    const float* __restrict__ x, unsigned short* __restrict__ xb,
    const float* __restrict__ W, unsigned short* __restrict__ Wt,
    const float* __restrict__ Wo, unsigned short* __restrict__ Wot,
    const int* __restrict__ ei, int* __restrict__ deg)
{
    const int b = blockIdx.x;
    if (b < CVTX_BLOCKS) {
        const int i = b * 256 + threadIdx.x;          // per float4, exact
        const float4 v = ((const float4*)x)[i];
        ushort4 o;
        o.x = f2bf(v.x); o.y = f2bf(v.y); o.z = f2bf(v.z); o.w = f2bf(v.w);
        ((ushort4*)xb)[i] = o;
    } else if (b < CVTX_BLOCKS + CVTW_BLOCKS) {
        // W[hd][k][o] -> Wt[hd*64+o][k]
        const int i = (b - CVTX_BLOCKS) * 256 + threadIdx.x;
        const int hd = i >> 14;
        const int o  = (i >> 8) & 63;
        const int k  = i & 255;
        Wt[i] = f2bf(W[((size_t)hd * IN_DIM + k) * HID + o]);
    } else if (b < CVTX_BLOCKS + CVTW_BLOCKS + CVTWO_BLOCKS) {
        // Wo[k][n] -> Wot[n][k]
        const int i = (b - CVTX_BLOCKS - CVTW_BLOCKS) * 256 + threadIdx.x;
        const int n = i >> 9;
        const int k = i & 511;
        Wot[i] = f2bf(Wo[(size_t)k * OUT_DIM + n]);
    } else {
        const int e = (b - CVTX_BLOCKS - CVTW_BLOCKS - CVTWO_BLOCKS) * 256 + threadIdx.x;
        if (e < N_EDGES) atomicAdd(&deg[ei[N_EDGES + e]], 1);
    }
}

// ---------------------------------------------------------------------------
// Unified MFMA GEMM: C[M][LDC] = A[M][K] @ Bt[N][K]^T  (tile 128x128, BK=64)
// Staging via explicit ds_write (R7 path — race-free through post-timing
// validation; R8's global_load_lds k-loop showed replay-timing divergence
// and was reverted).
// Fragment-order LDS: unit(row,g) = ((row>>4)*8+g)*16 + (row&15); frag read
// = units R*128 + kk*64 + lane (lane-linear, conflict-free).
// ---------------------------------------------------------------------------
template<int K, int LDC, int EPI>
__global__ __launch_bounds__(512) void gemm_mfma(
    const unsigned short* __restrict__ A,   // [M][K] bf16
    const unsigned short* __restrict__ Bt,  // [N][K] bf16
    const float* __restrict__ bias,
    void* __restrict__ Cv)
{
    const int m0 = blockIdx.x * 128;
    const int n0 = blockIdx.y * 128;
    const int tid = threadIdx.x;
    const int lane = tid & 63;
    const int w = tid >> 6;
    const int wr = w >> 2;          // 0..1 (M)
    const int wn = w & 3;           // 0..3 (N)
    __shared__ unsigned short lA[128 * 64];
    __shared__ unsigned short lB[128 * 64];

    const int c0 = tid,        r0 = c0 >> 3, g0 = c0 & 7;
    const int c1 = tid + 512,  r1 = c1 >> 3, g1 = c1 & 7;
    const int u0 = (((r0 >> 4) * 8 + g0) * 16) + (r0 & 15);
    const int u1 = (((r1 >> 4) * 8 + g1) * 16) + (r1 & 15);
    int am0 = m0 + r0; if (am0 >= N_NODES) am0 = N_NODES - 1;
    int am1 = m0 + r1; if (am1 >= N_NODES) am1 = N_NODES - 1;
    const unsigned short* Ap0 = A + (size_t)am0 * K + g0 * 8;
    const unsigned short* Ap1 = A + (size_t)am1 * K + g1 * 8;
    const unsigned short* Bp0 = Bt + (size_t)(n0 + r0) * K + g0 * 8;
    const unsigned short* Bp1 = Bt + (size_t)(n0 + r1) * K + g1 * 8;

    f32x4 acc[4][2];
    #pragma unroll
    for (int t = 0; t < 4; ++t)
        #pragma unroll
        for (int n = 0; n < 2; ++n) acc[t][n] = (f32x4){0,0,0,0};

    for (int k0 = 0; k0 < K; k0 += 64) {
        *(bf16x8*)(lA + u0 * 8) = *(const bf16x8*)(Ap0 + k0);
        *(bf16x8*)(lA + u1 * 8) = *(const bf16x8*)(Ap1 + k0);
        *(bf16x8*)(lB + u0 * 8) = *(const bf16x8*)(Bp0 + k0);
        *(bf16x8*)(lB + u1 * 8) = *(const bf16x8*)(Bp1 + k0);
        __syncthreads();
        #pragma unroll
        for (int kk = 0; kk < 2; ++kk) {
            bf16x8 bfr[2];
            #pragma unroll
            for (int n = 0; n < 2; ++n)
                bfr[n] = *(const bf16x8*)(lB + ((wn * 2 + n) * 128 + kk * 64 + lane) * 8);
            #pragma unroll
            for (int t = 0; t < 4; ++t) {
                const bf16x8 afr = *(const bf16x8*)(lA + ((wr * 4 + t) * 128 + kk * 64 + lane) * 8);
                #pragma unroll
                for (int n = 0; n < 2; ++n)
                    acc[t][n] = __builtin_amdgcn_mfma_f32_16x16x32_bf16(afr, bfr[n], acc[t][n], 0, 0, 0);
            }
        }
        __syncthreads();
    }

    #pragma unroll
    for (int n = 0; n < 2; ++n) {
        const int col = n0 + wn * 32 + n * 16 + (lane & 15);
        float b = 0.0f;
        if (EPI == 1) b = bias[col];
        #pragma unroll
        for (int t = 0; t < 4; ++t) {
            #pragma unroll
            for (int r = 0; r < 4; ++r) {
                const int m = m0 + wr * 64 + t * 16 + ((lane >> 4) << 2) + r;
                if (m < N_NODES) {
                    const float v = acc[t][n][r];
                    if (EPI == 0) {
                        ((unsigned short*)Cv)[(size_t)m * LDC + col] = f2bf(v);
                    } else {
                        float z = v + b;
                        ((float*)Cv)[(size_t)m * LDC + col] = (z > 0.0f) ? z : expm1f(z);
                    }
                }
            }
        }
    }
}

// ---------------------------------------------------------------------------
// s projections from bf16 h
// ---------------------------------------------------------------------------
__global__ __launch_bounds__(256) void s_kernel(
    const unsigned short* __restrict__ hb, const float* __restrict__ a,
    float* __restrict__ s_src, float* __restrict__ s_tgt)
{
    const int n = blockIdx.x * 4 + (threadIdx.x >> 6);
    const int lane = threadIdx.x & 63;
    if (n >= N_NODES) return;
    const int hd = lane >> 3;
    const int seg = lane & 7;
    const bf16x8 hv = *(const bf16x8*)(hb + (size_t)n * 512 + lane * 8);
    float p = 0.0f, q = 0.0f;
    #pragma unroll
    for (int j = 0; j < 8; ++j) {
        const float hf = bf2f((unsigned short)hv[j]);
        p = fmaf(hf, a[hd * 128 + seg * 8 + j], p);
        q = fmaf(hf, a[hd * 128 + 64 + seg * 8 + j], q);
    }
    #pragma unroll
    for (int off = 1; off < 8; off <<= 1) {
        p += __shfl_xor(p, off);
        q += __shfl_xor(q, off);
    }
    if (seg == 0) {
        s_src[(size_t)n * 8 + hd] = p;
        s_tgt[(size_t)n * 8 + hd] = q;
    }
}

// ---------------------------------------------------------------------------
// Hierarchical scan (2 kernels) + fill
// ---------------------------------------------------------------------------
__global__ __launch_bounds__(256) void scan_block_sum(
    const int* __restrict__ deg, int* __restrict__ bsum)
{
    const int i = blockIdx.x * 256 + threadIdx.x;
    int v = (i < N_NODES) ? deg[i] : 0;
    __shared__ int ws_[4];
    #pragma unroll
    for (int off = 32; off > 0; off >>= 1) v += __shfl_down(v, off);
    if ((threadIdx.x & 63) == 0) ws_[threadIdx.x >> 6] = v;
    __syncthreads();
    if (threadIdx.x == 0) bsum[blockIdx.x] = ws_[0] + ws_[1] + ws_[2] + ws_[3];
}

// per-block: reduce bsum[j < blockIdx] for the cross-block prefix, then
// block-local exclusive scan of deg.
__global__ __launch_bounds__(256) void scan_final(
    const int* __restrict__ deg, const int* __restrict__ bsum,
    int* __restrict__ base)
{
    const int i = blockIdx.x * 256 + threadIdx.x;
    const int t = threadIdx.x;
    __shared__ int wsum[4];
    int bv = (t < NSB && t < blockIdx.x) ? bsum[t] : 0;
    #pragma unroll
    for (int off = 32; off > 0; off >>= 1) bv += __shfl_down(bv, off);
    if ((t & 63) == 0) wsum[t >> 6] = bv;
    __syncthreads();
    const int pre = wsum[0] + wsum[1] + wsum[2] + wsum[3];

    const int v = (i < N_NODES) ? deg[i] : 0;
    __shared__ int s[256];
    s[t] = v;
    __syncthreads();
    for (int off = 1; off < 256; off <<= 1) {
        int u = (t >= off) ? s[t - off] : 0;
        __syncthreads();
        s[t] += u;
        __syncthreads();
    }
    if (i < N_NODES) base[i] = pre + s[t] - v;
}

__global__ __launch_bounds__(256) void fill_kernel(
    const int* __restrict__ ei, int* __restrict__ base,
    int* __restrict__ csr_src)
{
    const int e = blockIdx.x * 256 + threadIdx.x;
    if (e >= N_EDGES) return;
    const int src = ei[e];
    const int tgt = ei[N_EDGES + e];
    const int pos = atomicAdd(&base[tgt], 1);
    csr_src[pos] = src;
}

// ---------------------------------------------------------------------------
// Fused segment kernel v3: one wave per target node.
// Full 8-edge batches take an 8-deep load path (8KB in flight / wave).
// ALL __shfl at wave-uniform control flow (R6 lesson).
// ---------------------------------------------------------------------------
__global__ __launch_bounds__(256) void segment_kernel(
    const int* __restrict__ endoff, const int* __restrict__ csr_src,
    const float* __restrict__ s_src, const float* __restrict__ s_tgt,
    const unsigned short* __restrict__ hb, unsigned short* __restrict__ accb)
{
    const int t = blockIdx.x * 4 + (threadIdx.x >> 6);
    const int lane = threadIdx.x & 63;
    if (t >= N_NODES) return;
    const int e0 = (t == 0) ? 0 : endoff[t - 1];
    const int e1 = endoff[t];
    const int myhead = lane >> 3;    // head owned in gather/output
    const int islot = lane >> 3;     // edge slot in pv batch (same bits)
    const int pj = lane & 7;         // head in pv batch

    const float st = s_tgt[(size_t)t * 8 + pj];

    float dsum = 0.0f;               // partial denom: (slot islot, head pj)
    float msg[8] = {};
    for (int ebase = e0; ebase < e1; ebase += 64) {
        const int cnt = min(64, e1 - ebase);
        int my_src = 0;
        if (lane < cnt) my_src = csr_src[ebase + lane];
        const int nfull = cnt >> 3;
        for (int b = 0; b < nfull; ++b) {
            // all 8 slots valid: uniform, branch-free
            const int esrc = __shfl(my_src, b * 8 + islot);
            float v = s_src[(size_t)esrc * 8 + pj] + st;
            v = (v >= 0.0f) ? v : NEG_SLOPE * v;
            const float pv = expf(v);
            dsum += pv;
            int  sr[8]; float al[8]; bf16x8 hv[8];
            #pragma unroll
            for (int u = 0; u < 8; ++u) {
                sr[u] = __shfl(my_src, b * 8 + u);
                al[u] = __shfl(pv, u * 8 + myhead);
            }
            #pragma unroll
            for (int u = 0; u < 8; ++u)
                hv[u] = *(const bf16x8*)(hb + (size_t)sr[u] * 512 + lane * 8);
            #pragma unroll
            for (int u = 0; u < 8; ++u)
                #pragma unroll
                for (int j = 0; j < 8; ++j)
                    msg[j] = fmaf(bf2f((unsigned short)hv[u][j]), al[u], msg[j]);
        }
        // tail batch (nb < 8)
        const int tb = nfull * 8;
        const int nb = cnt - tb;
        if (nb > 0) {
            const int esrc = __shfl(my_src, tb + islot);   // uniform exec
            float pv = 0.0f;
            if (islot < nb) {
                float v = s_src[(size_t)esrc * 8 + pj] + st;
                v = (v >= 0.0f) ? v : NEG_SLOPE * v;
                pv = expf(v);
            }
            dsum += pv;
            for (int i = 0; i < nb; ++i) {
                const int src = __shfl(my_src, tb + i);
                const float al = __shfl(pv, i * 8 + myhead);
                const bf16x8 hv = *(const bf16x8*)(hb + (size_t)src * 512 + lane * 8);
                #pragma unroll
                for (int j = 0; j < 8; ++j)
                    msg[j] = fmaf(bf2f((unsigned short)hv[j]), al, msg[j]);
            }
        }
    }
    // cross-slot denom reduce: lane l -> full denom for head l&7
    dsum += __shfl_xor(dsum, 8);
    dsum += __shfl_xor(dsum, 16);
    dsum += __shfl_xor(dsum, 32);
    const float d = __shfl(dsum, myhead) + 1e-16f;   // denom for head l>>3
    bf16x8 ov;
    #pragma unroll
    for (int j = 0; j < 8; ++j) ov[j] = (short)f2bf(msg[j] / d);
    *(bf16x8*)(accb + (size_t)t * 512 + lane * 8) = ov;
}

// ---------------------------------------------------------------------------
extern "C" void kernel_launch(void* const* d_in, const int* in_sizes, int n_in,
                              void* d_out, int out_size, void* d_ws, size_t ws_size,
                              hipStream_t stream) {
    const float* x   = (const float*)d_in[0];
    const int*   ei  = (const int*)d_in[1];
    const float* W   = (const float*)d_in[2];
    const float* a   = (const float*)d_in[3];
    const float* Wo  = (const float*)d_in[4];
    const float* bo  = (const float*)d_in[5];
    float* out = (float*)d_out;

    // workspace: hb | xb | accb | Wt | Wot | s_src | s_tgt | deg|base|csr|bsum
    unsigned short* hb   = (unsigned short*)d_ws;
    const size_t hsz = (size_t)N_NODES * HEADS * HID;        // 25.6M elems
    unsigned short* xb   = hb + hsz;
    unsigned short* accb = xb + (size_t)N_NODES * IN_DIM;
    unsigned short* Wt   = accb + hsz;
    unsigned short* Wot  = Wt + (size_t)HEADS * HID * IN_DIM;
    float* s_src = (float*)(Wot + (size_t)(HEADS * HID) * OUT_DIM);
    float* s_tgt = s_src + (size_t)N_NODES * HEADS;
    int* deg  = (int*)(s_tgt + (size_t)N_NODES * HEADS);
    int* base = deg + N_NODES;
    int* csr  = base + N_NODES;
    int* bsum = csr + N_EDGES;

    hipMemsetAsync(deg, 0, N_NODES * sizeof(int), stream);

    prep_kernel<<<CVTX_BLOCKS + CVTW_BLOCKS + CVTWO_BLOCKS + HIST_BLOCKS,
                  256, 0, stream>>>(x, xb, W, Wt, Wo, Wot, ei, deg);

    scan_block_sum<<<NSB, 256, 0, stream>>>(deg, bsum);
    scan_final<<<NSB, 256, 0, stream>>>(deg, bsum, base);
    fill_kernel<<<(N_EDGES + 255) / 256, 256, 0, stream>>>(ei, base, csr);

    // h = x @ W  (bf16 out), single GEMM over folded heads
    dim3 g1((N_NODES + 127) / 128, (HEADS * HID) / 128);
    gemm_mfma<IN_DIM, HEADS * HID, 0><<<g1, 512, 0, stream>>>(xb, Wt, nullptr, hb);

    s_kernel<<<(N_NODES + 3) / 4, 256, 0, stream>>>(hb, a, s_src, s_tgt);

    segment_kernel<<<(N_NODES + 3) / 4, 256, 0, stream>>>(
        base, csr, s_src, s_tgt, hb, accb);

    // out = elu(acc @ Wo + bo)
    dim3 g5((N_NODES + 127) / 128, OUT_DIM / 128);
    gemm_mfma<HEADS * HID, OUT_DIM, 1><<<g5, 512, 0, stream>>>(accb, Wot, bo, out);
}

// Round 11
// 229.162 us; speedup vs baseline: 6.1822x; 1.0139x over previous
//
#include <hip/hip_runtime.h>
#include <hip/hip_bf16.h>
#include <math.h>

#define N_NODES 50000
#define N_EDGES 400000
#define IN_DIM 256
#define HID 64
#define HEADS 8
#define OUT_DIM 256
#define NEG_SLOPE 0.2f
#define NSB ((N_NODES + 255) / 256)   // 196 scan blocks

// prep_kernel block ranges
#define CVTX_BLOCKS 12500             // 50000*256/4/256 exact
#define CVTW_BLOCKS 512               // 131072/256 exact
#define CVTWO_BLOCKS 512
#define HIST_BLOCKS 1563

typedef __attribute__((ext_vector_type(8))) short bf16x8;
typedef __attribute__((ext_vector_type(4))) float f32x4;

// RNE float->bf16
static __device__ __forceinline__ unsigned short f2bf(float f) {
    unsigned int u = __float_as_uint(f);
    unsigned int r = (u + 0x7fffu + ((u >> 16) & 1u)) >> 16;
    return (unsigned short)r;
}
static __device__ __forceinline__ float bf2f(unsigned short s) {
    return __uint_as_float((unsigned int)s << 16);
}

// ---------------------------------------------------------------------------
// Fused prologue: cvt_x | cvt_w | cvt_wo | hist by blockIdx range.
// ---------------------------------------------------------------------------
__global__ __launch_bounds__(256) void prep_kernel(
    const float* __restrict__ x, unsigned short* __restrict__ xb,
    const float* __restrict__ W, unsigned short* __restrict__ Wt,
    const float* __restrict__ Wo, unsigned short* __restrict__ Wot,
    const int* __restrict__ ei, int* __restrict__ deg)
{
    const int b = blockIdx.x;
    if (b < CVTX_BLOCKS) {
        const int i = b * 256 + threadIdx.x;          // per float4, exact
        const float4 v = ((const float4*)x)[i];
        ushort4 o;
        o.x = f2bf(v.x); o.y = f2bf(v.y); o.z = f2bf(v.z); o.w = f2bf(v.w);
        ((ushort4*)xb)[i] = o;
    } else if (b < CVTX_BLOCKS + CVTW_BLOCKS) {
        // W[hd][k][o] -> Wt[hd*64+o][k]
        const int i = (b - CVTX_BLOCKS) * 256 + threadIdx.x;
        const int hd = i >> 14;
        const int o  = (i >> 8) & 63;
        const int k  = i & 255;
        Wt[i] = f2bf(W[((size_t)hd * IN_DIM + k) * HID + o]);
    } else if (b < CVTX_BLOCKS + CVTW_BLOCKS + CVTWO_BLOCKS) {
        // Wo[k][n] -> Wot[n][k]
        const int i = (b - CVTX_BLOCKS - CVTW_BLOCKS) * 256 + threadIdx.x;
        const int n = i >> 9;
        const int k = i & 511;
        Wot[i] = f2bf(Wo[(size_t)k * OUT_DIM + n]);
    } else {
        const int e = (b - CVTX_BLOCKS - CVTW_BLOCKS - CVTWO_BLOCKS) * 256 + threadIdx.x;
        if (e < N_EDGES) atomicAdd(&deg[ei[N_EDGES + e]], 1);
    }
}

// ---------------------------------------------------------------------------
// Unified MFMA GEMM: C[M][LDC] = A[M][K] @ Bt[N][K]^T  (tile 128x128, BK=64)
// ds_write staging (race-free through post-timing validation) + 2-phase
// REGISTER prefetch: next k-tile's 4 chunks load right after the first
// barrier, hiding HBM latency under the 16 MFMAs. Numerically identical
// to the R9 loop (same MFMA sequence on same data).
// Fragment-order LDS: unit(row,g) = ((row>>4)*8+g)*16 + (row&15); frag read
// = units R*128 + kk*64 + lane (lane-linear, conflict-free).
// EPI 0: store C bf16.  EPI 1: +bias, elu, store f32.
// (R10's fused s-projection epilogue caused absmax 0.102 — removed.)
// ---------------------------------------------------------------------------
template<int K, int LDC, int EPI>
__global__ __launch_bounds__(512) void gemm_mfma(
    const unsigned short* __restrict__ A,   // [M][K] bf16
    const unsigned short* __restrict__ Bt,  // [N][K] bf16
    const float* __restrict__ bias,
    void* __restrict__ Cv)
{
    const int m0 = blockIdx.x * 128;
    const int n0 = blockIdx.y * 128;
    const int tid = threadIdx.x;
    const int lane = tid & 63;
    const int w = tid >> 6;
    const int wr = w >> 2;          // 0..1 (M)
    const int wn = w & 3;           // 0..3 (N)
    __shared__ unsigned short lA[128 * 64];
    __shared__ unsigned short lB[128 * 64];

    const int c0 = tid,        r0 = c0 >> 3, g0 = c0 & 7;
    const int c1 = tid + 512,  r1 = c1 >> 3, g1 = c1 & 7;
    const int u0 = (((r0 >> 4) * 8 + g0) * 16) + (r0 & 15);
    const int u1 = (((r1 >> 4) * 8 + g1) * 16) + (r1 & 15);
    int am0 = m0 + r0; if (am0 >= N_NODES) am0 = N_NODES - 1;
    int am1 = m0 + r1; if (am1 >= N_NODES) am1 = N_NODES - 1;
    const unsigned short* Ap0 = A + (size_t)am0 * K + g0 * 8;
    const unsigned short* Ap1 = A + (size_t)am1 * K + g1 * 8;
    const unsigned short* Bp0 = Bt + (size_t)(n0 + r0) * K + g0 * 8;
    const unsigned short* Bp1 = Bt + (size_t)(n0 + r1) * K + g1 * 8;

    f32x4 acc[4][2];
    #pragma unroll
    for (int t = 0; t < 4; ++t)
        #pragma unroll
        for (int n = 0; n < 2; ++n) acc[t][n] = (f32x4){0,0,0,0};

    // prefetch k-tile 0
    bf16x8 rA0 = *(const bf16x8*)(Ap0);
    bf16x8 rA1 = *(const bf16x8*)(Ap1);
    bf16x8 rB0 = *(const bf16x8*)(Bp0);
    bf16x8 rB1 = *(const bf16x8*)(Bp1);

    for (int k0 = 0; k0 < K; k0 += 64) {
        *(bf16x8*)(lA + u0 * 8) = rA0;
        *(bf16x8*)(lA + u1 * 8) = rA1;
        *(bf16x8*)(lB + u0 * 8) = rB0;
        *(bf16x8*)(lB + u1 * 8) = rB1;
        __syncthreads();
        if (k0 + 64 < K) {          // uniform branch: prefetch next k-tile
            rA0 = *(const bf16x8*)(Ap0 + k0 + 64);
            rA1 = *(const bf16x8*)(Ap1 + k0 + 64);
            rB0 = *(const bf16x8*)(Bp0 + k0 + 64);
            rB1 = *(const bf16x8*)(Bp1 + k0 + 64);
        }
        #pragma unroll
        for (int kk = 0; kk < 2; ++kk) {
            bf16x8 bfr[2];
            #pragma unroll
            for (int n = 0; n < 2; ++n)
                bfr[n] = *(const bf16x8*)(lB + ((wn * 2 + n) * 128 + kk * 64 + lane) * 8);
            #pragma unroll
            for (int t = 0; t < 4; ++t) {
                const bf16x8 afr = *(const bf16x8*)(lA + ((wr * 4 + t) * 128 + kk * 64 + lane) * 8);
                #pragma unroll
                for (int n = 0; n < 2; ++n)
                    acc[t][n] = __builtin_amdgcn_mfma_f32_16x16x32_bf16(afr, bfr[n], acc[t][n], 0, 0, 0);
            }
        }
        __syncthreads();
    }

    #pragma unroll
    for (int n = 0; n < 2; ++n) {
        const int col = n0 + wn * 32 + n * 16 + (lane & 15);
        float b = 0.0f;
        if (EPI == 1) b = bias[col];
        #pragma unroll
        for (int t = 0; t < 4; ++t) {
            #pragma unroll
            for (int r = 0; r < 4; ++r) {
                const int m = m0 + wr * 64 + t * 16 + ((lane >> 4) << 2) + r;
                if (m < N_NODES) {
                    const float v = acc[t][n][r];
                    if (EPI == 0) {
                        ((unsigned short*)Cv)[(size_t)m * LDC + col] = f2bf(v);
                    } else {
                        float z = v + b;
                        ((float*)Cv)[(size_t)m * LDC + col] = (z > 0.0f) ? z : expm1f(z);
                    }
                }
            }
        }
    }
}

// ---------------------------------------------------------------------------
// s projections from bf16 h (standalone — R9 path, validated)
// ---------------------------------------------------------------------------
__global__ __launch_bounds__(256) void s_kernel(
    const unsigned short* __restrict__ hb, const float* __restrict__ a,
    float* __restrict__ s_src, float* __restrict__ s_tgt)
{
    const int n = blockIdx.x * 4 + (threadIdx.x >> 6);
    const int lane = threadIdx.x & 63;
    if (n >= N_NODES) return;
    const int hd = lane >> 3;
    const int seg = lane & 7;
    const bf16x8 hv = *(const bf16x8*)(hb + (size_t)n * 512 + lane * 8);
    float p = 0.0f, q = 0.0f;
    #pragma unroll
    for (int j = 0; j < 8; ++j) {
        const float hf = bf2f((unsigned short)hv[j]);
        p = fmaf(hf, a[hd * 128 + seg * 8 + j], p);
        q = fmaf(hf, a[hd * 128 + 64 + seg * 8 + j], q);
    }
    #pragma unroll
    for (int off = 1; off < 8; off <<= 1) {
        p += __shfl_xor(p, off);
        q += __shfl_xor(q, off);
    }
    if (seg == 0) {
        s_src[(size_t)n * 8 + hd] = p;
        s_tgt[(size_t)n * 8 + hd] = q;
    }
}

// ---------------------------------------------------------------------------
// Hierarchical scan (2 kernels) + fill
// ---------------------------------------------------------------------------
__global__ __launch_bounds__(256) void scan_block_sum(
    const int* __restrict__ deg, int* __restrict__ bsum)
{
    const int i = blockIdx.x * 256 + threadIdx.x;
    int v = (i < N_NODES) ? deg[i] : 0;
    __shared__ int ws_[4];
    #pragma unroll
    for (int off = 32; off > 0; off >>= 1) v += __shfl_down(v, off);
    if ((threadIdx.x & 63) == 0) ws_[threadIdx.x >> 6] = v;
    __syncthreads();
    if (threadIdx.x == 0) bsum[blockIdx.x] = ws_[0] + ws_[1] + ws_[2] + ws_[3];
}

__global__ __launch_bounds__(256) void scan_final(
    const int* __restrict__ deg, const int* __restrict__ bsum,
    int* __restrict__ base)
{
    const int i = blockIdx.x * 256 + threadIdx.x;
    const int t = threadIdx.x;
    __shared__ int wsum[4];
    int bv = (t < NSB && t < blockIdx.x) ? bsum[t] : 0;
    #pragma unroll
    for (int off = 32; off > 0; off >>= 1) bv += __shfl_down(bv, off);
    if ((t & 63) == 0) wsum[t >> 6] = bv;
    __syncthreads();
    const int pre = wsum[0] + wsum[1] + wsum[2] + wsum[3];

    const int v = (i < N_NODES) ? deg[i] : 0;
    __shared__ int s[256];
    s[t] = v;
    __syncthreads();
    for (int off = 1; off < 256; off <<= 1) {
        int u = (t >= off) ? s[t - off] : 0;
        __syncthreads();
        s[t] += u;
        __syncthreads();
    }
    if (i < N_NODES) base[i] = pre + s[t] - v;
}

__global__ __launch_bounds__(256) void fill_kernel(
    const int* __restrict__ ei, int* __restrict__ base,
    int* __restrict__ csr_src)
{
    const int e = blockIdx.x * 256 + threadIdx.x;
    if (e >= N_EDGES) return;
    const int src = ei[e];
    const int tgt = ei[N_EDGES + e];
    const int pos = atomicAdd(&base[tgt], 1);
    csr_src[pos] = src;
}

// ---------------------------------------------------------------------------
// Fused segment kernel (R7 v2 — measured best: 67.6us, occupancy 52%).
// alpha batched 8-edges-wide; all __shfl at wave-uniform control flow.
// ---------------------------------------------------------------------------
__global__ __launch_bounds__(256) void segment_kernel(
    const int* __restrict__ endoff, const int* __restrict__ csr_src,
    const float* __restrict__ s_src, const float* __restrict__ s_tgt,
    const unsigned short* __restrict__ hb, unsigned short* __restrict__ accb)
{
    const int t = blockIdx.x * 4 + (threadIdx.x >> 6);
    const int lane = threadIdx.x & 63;
    if (t >= N_NODES) return;
    const int e0 = (t == 0) ? 0 : endoff[t - 1];
    const int e1 = endoff[t];
    const int myhead = lane >> 3;    // head owned in gather/output
    const int islot = lane >> 3;     // edge slot in pv batch (same bits)
    const int pj = lane & 7;         // head in pv batch

    const float st = s_tgt[(size_t)t * 8 + pj];

    float dsum = 0.0f;               // partial denom: (slot islot, head pj)
    float msg[8] = {};
    for (int ebase = e0; ebase < e1; ebase += 64) {
        const int cnt = min(64, e1 - ebase);
        int my_src = 0;
        if (lane < cnt) my_src = csr_src[ebase + lane];
        for (int b = 0; b * 8 < cnt; ++b) {
            const int nb = min(8, cnt - b * 8);
            // shfl OUTSIDE the divergent if (uniform exec -> all lanes publish)
            const int esrc = __shfl(my_src, b * 8 + islot);
            float pv = 0.0f;
            if (islot < nb) {
                float v = s_src[(size_t)esrc * 8 + pj] + st;
                v = (v >= 0.0f) ? v : NEG_SLOPE * v;
                pv = expf(v);
            }
            dsum += pv;
            // gather + weighted accumulate, unroll x4 for MLP
            int i = 0;
            for (; i + 4 <= nb; i += 4) {
                int  sr[4]; float al[4]; bf16x8 hv[4];
                #pragma unroll
                for (int u = 0; u < 4; ++u) {
                    sr[u] = __shfl(my_src, b * 8 + i + u);
                    al[u] = __shfl(pv, (i + u) * 8 + myhead);
                }
                #pragma unroll
                for (int u = 0; u < 4; ++u)
                    hv[u] = *(const bf16x8*)(hb + (size_t)sr[u] * 512 + lane * 8);
                #pragma unroll
                for (int u = 0; u < 4; ++u)
                    #pragma unroll
                    for (int j = 0; j < 8; ++j)
                        msg[j] = fmaf(bf2f((unsigned short)hv[u][j]), al[u], msg[j]);
            }
            for (; i < nb; ++i) {
                const int src = __shfl(my_src, b * 8 + i);
                const float al = __shfl(pv, i * 8 + myhead);
                const bf16x8 hv = *(const bf16x8*)(hb + (size_t)src * 512 + lane * 8);
                #pragma unroll
                for (int j = 0; j < 8; ++j)
                    msg[j] = fmaf(bf2f((unsigned short)hv[j]), al, msg[j]);
            }
        }
    }
    // cross-slot denom reduce: lane l -> full denom for head l&7
    dsum += __shfl_xor(dsum, 8);
    dsum += __shfl_xor(dsum, 16);
    dsum += __shfl_xor(dsum, 32);
    const float d = __shfl(dsum, myhead) + 1e-16f;   // denom for head l>>3
    bf16x8 ov;
    #pragma unroll
    for (int j = 0; j < 8; ++j) ov[j] = (short)f2bf(msg[j] / d);
    *(bf16x8*)(accb + (size_t)t * 512 + lane * 8) = ov;
}

// ---------------------------------------------------------------------------
extern "C" void kernel_launch(void* const* d_in, const int* in_sizes, int n_in,
                              void* d_out, int out_size, void* d_ws, size_t ws_size,
                              hipStream_t stream) {
    const float* x   = (const float*)d_in[0];
    const int*   ei  = (const int*)d_in[1];
    const float* W   = (const float*)d_in[2];
    const float* a   = (const float*)d_in[3];
    const float* Wo  = (const float*)d_in[4];
    const float* bo  = (const float*)d_in[5];
    float* out = (float*)d_out;

    // workspace: hb | xb | accb | Wt | Wot | s_src | s_tgt | deg|base|csr|bsum
    unsigned short* hb   = (unsigned short*)d_ws;
    const size_t hsz = (size_t)N_NODES * HEADS * HID;        // 25.6M elems
    unsigned short* xb   = hb + hsz;
    unsigned short* accb = xb + (size_t)N_NODES * IN_DIM;
    unsigned short* Wt   = accb + hsz;
    unsigned short* Wot  = Wt + (size_t)HEADS * HID * IN_DIM;
    float* s_src = (float*)(Wot + (size_t)(HEADS * HID) * OUT_DIM);
    float* s_tgt = s_src + (size_t)N_NODES * HEADS;
    int* deg  = (int*)(s_tgt + (size_t)N_NODES * HEADS);
    int* base = deg + N_NODES;
    int* csr  = base + N_NODES;
    int* bsum = csr + N_EDGES;

    hipMemsetAsync(deg, 0, N_NODES * sizeof(int), stream);

    prep_kernel<<<CVTX_BLOCKS + CVTW_BLOCKS + CVTWO_BLOCKS + HIST_BLOCKS,
                  256, 0, stream>>>(x, xb, W, Wt, Wo, Wot, ei, deg);

    scan_block_sum<<<NSB, 256, 0, stream>>>(deg, bsum);
    scan_final<<<NSB, 256, 0, stream>>>(deg, bsum, base);
    fill_kernel<<<(N_EDGES + 255) / 256, 256, 0, stream>>>(ei, base, csr);

    // h = x @ W  (bf16 out), single GEMM over folded heads
    dim3 g1((N_NODES + 127) / 128, (HEADS * HID) / 128);
    gemm_mfma<IN_DIM, HEADS * HID, 0><<<g1, 512, 0, stream>>>(xb, Wt, nullptr, hb);

    s_kernel<<<(N_NODES + 3) / 4, 256, 0, stream>>>(hb, a, s_src, s_tgt);

    segment_kernel<<<(N_NODES + 3) / 4, 256, 0, stream>>>(
        base, csr, s_src, s_tgt, hb, accb);

    // out = elu(acc @ Wo + bo)
    dim3 g5((N_NODES + 127) / 128, OUT_DIM / 128);
    gemm_mfma<HEADS * HID, OUT_DIM, 1><<<g5, 512, 0, stream>>>(accb, Wot, bo, out);
}